// Round 5
// baseline (3180.097 us; speedup 1.0000x reference)
//
#include <hip/hip_runtime.h>
#include <hip/hip_bf16.h>
#include <math.h>

#define D_MODEL 768
#define N_HEAD  12
#define HEAD    64
#define SEQ     1024
#define NLAYER  6
#define BATCH   4
#define NROWS   (BATCH*SEQ)   // 4096
#define VOCAB   50257
#define VPAD    50304         // 393*128
#define DFFN    3072
#define DQKV    2304

typedef __attribute__((ext_vector_type(8))) __bf16 bf16x8;
typedef __attribute__((ext_vector_type(4))) float f32x4;
typedef __attribute__((ext_vector_type(4))) unsigned short u16x4;

__device__ inline unsigned short f2bf(float x) {
    __hip_bfloat16 h = __float2bfloat16(x);
    return *reinterpret_cast<unsigned short*>(&h);
}

// ---------------- embedding ----------------
__global__ __launch_bounds__(256)
void embed_kernel(const int* __restrict__ idx, const float* __restrict__ tok,
                  const float* __restrict__ pos, float* __restrict__ x) {
    int row = blockIdx.x;
    int t = idx[row];
    int s = row & (SEQ - 1);
    const float* tp = tok + (size_t)t * D_MODEL;
    const float* pp = pos + (size_t)s * D_MODEL;
    float* xp = x + (size_t)row * D_MODEL;
    for (int i = threadIdx.x; i < D_MODEL; i += 256) xp[i] = tp[i] + pp[i];
}

// ---------------- layernorm: fp32 in, bf16 out ----------------
__global__ __launch_bounds__(256)
void ln_kernel(const float* __restrict__ in, const float* __restrict__ gw,
               const float* __restrict__ bw, unsigned short* __restrict__ out) {
    int row = blockIdx.x;
    int tid = threadIdx.x;
    const float* x = in + (size_t)row * D_MODEL;
    float v0 = x[tid], v1 = x[tid + 256], v2 = x[tid + 512];
    float s  = v0 + v1 + v2;
    float sq = v0*v0 + v1*v1 + v2*v2;
    #pragma unroll
    for (int o = 1; o < 64; o <<= 1) { s += __shfl_xor(s, o); sq += __shfl_xor(sq, o); }
    __shared__ float red[8];
    int wave = tid >> 6;
    if ((tid & 63) == 0) { red[wave] = s; red[4 + wave] = sq; }
    __syncthreads();
    s  = red[0] + red[1] + red[2] + red[3];
    sq = red[4] + red[5] + red[6] + red[7];
    float mean = s * (1.0f / D_MODEL);
    float var  = sq * (1.0f / D_MODEL) - mean * mean;
    float rstd = rsqrtf(var + 1e-5f);
    unsigned short* op = out + (size_t)row * D_MODEL;
    op[tid]       = f2bf((v0 - mean) * rstd * gw[tid]       + bw[tid]);
    op[tid + 256] = f2bf((v1 - mean) * rstd * gw[tid + 256] + bw[tid + 256]);
    op[tid + 512] = f2bf((v2 - mean) * rstd * gw[tid + 512] + bw[tid + 512]);
}

// ---------------- weight conversion ----------------
template<int MODE>
__global__ __launch_bounds__(256)
void conv_transpose(const float* __restrict__ in, unsigned short* __restrict__ out,
                    int K, int N, size_t inLstride, size_t outLstride) {
    __shared__ float t[32][33];
    const int tx = threadIdx.x, ty = threadIdx.y;
    const int n0 = blockIdx.x * 32, k0 = blockIdx.y * 32;
    const float* ip = in + blockIdx.z * inLstride;
    unsigned short* op = out + blockIdx.z * outLstride;
    #pragma unroll
    for (int j = 0; j < 4; ++j) {
        int k = k0 + ty + j * 8, n = n0 + tx;
        float v = (MODE == 0) ? ip[(size_t)k * N + n]
                              : ip[(size_t)((n >> 6) * K + k) * 64 + (n & 63)];
        t[ty + j * 8][tx] = v;
    }
    __syncthreads();
    #pragma unroll
    for (int j = 0; j < 4; ++j) {
        int n = n0 + ty + j * 8, k = k0 + tx;
        op[(size_t)n * K + k] = f2bf(t[tx][ty + j * 8]);
    }
}

__global__ __launch_bounds__(256)
void conv_lm(const float* __restrict__ in, unsigned short* __restrict__ out) {
    const int nchunks = VPAD * D_MODEL / 4;
    const int vchunks = VOCAB * D_MODEL / 4;
    for (int i = blockIdx.x * 256 + threadIdx.x; i < nchunks; i += gridDim.x * 256) {
        u16x4 o;
        if (i < vchunks) {
            float4 v = reinterpret_cast<const float4*>(in)[i];
            o[0] = f2bf(v.x); o[1] = f2bf(v.y); o[2] = f2bf(v.z); o[3] = f2bf(v.w);
        } else { o[0] = 0; o[1] = 0; o[2] = 0; o[3] = 0; }
        reinterpret_cast<u16x4*>(out)[i] = o;
    }
}

__global__ __launch_bounds__(256)
void conv_bias(const float* __restrict__ bq, const float* __restrict__ bk,
               const float* __restrict__ bv, float* __restrict__ out) {
    int i = blockIdx.x * 256 + threadIdx.x;
    if (i >= NLAYER * DQKV) return;
    int l = i / DQKV, n = i % DQKV;
    float v;
    if (n < 768)        v = bq[l * 768 + n];
    else if (n < 1536)  v = bk[l * 768 + n - 768];
    else                v = bv[l * 768 + n - 1536];
    out[i] = v;
}

// ---------------- bf16 MFMA GEMM, issue-early double-buffered ----------------
// C[M,N] = A[M,K](bf16) @ B[N,K](bf16)^T + bias (+GELU) (+res)
// 1D grid, nwg = (M/BM)*(N/128), nwg%8==0, (M/BM)%8==0, (K/64) even.
// Pipeline: stage(t+1,other_buf) issued BEFORE compute(t) so the barrier's
// vmcnt(0) drain lands after a full compute phase (T3 minimum-2-phase recipe).
template<int BM, int OUTF /*0=f32,1=bf16*/, bool GELU, bool RES>
__global__ __launch_bounds__(256)
void gemm_mfma(const unsigned short* __restrict__ A, const unsigned short* __restrict__ B,
               const float* __restrict__ bias, const float* __restrict__ res,
               void* __restrict__ Cout, int M, int N, int K) {
    constexpr int ACH = BM * 8;          // bf16x8 chunks per A tile
    __shared__ bf16x8 As[2][ACH];
    __shared__ bf16x8 Bs[2][1024];
    // XCD-contiguous chunks; by fastest within groups of 8 rows, bx slow.
    const int nwg = gridDim.x;
    const int t0 = (blockIdx.x & 7) * (nwg >> 3) + (blockIdx.x >> 3);
    const int MT = M / BM;
    const int NBX = nwg / MT;
    const int srsize = NBX * 8;
    const int sr = t0 / srsize;
    const int rem = t0 - sr * srsize;
    const int bx = rem >> 3;
    const int by = sr * 8 + (rem & 7);
    const int bm = by * BM, bn = bx * 128;
    const int tid = threadIdx.x;
    const int l = tid & 63, w = tid >> 6;
    constexpr int MI = (BM == 128) ? 4 : 2;
    const int wr = (BM == 128) ? (w >> 1) * 64 : (w & 1) * 32;
    const int wc = (BM == 128) ? (w & 1) * 64 : (w >> 1) * 64;
    f32x4 acc[MI][4] = {};

    auto stage = [&](int k0, int sel) {
        #pragma unroll
        for (int p = 0; p < ACH / 256; ++p) {
            int u = p * 256 + tid;
            int row = u % BM, c = u / BM;
            const unsigned short* ga = A + (size_t)(bm + row) * K + k0 + c * 8;
            __builtin_amdgcn_global_load_lds(
                (const __attribute__((address_space(1))) unsigned int*)ga,
                (__attribute__((address_space(3))) unsigned int*)(&As[sel][u]), 16, 0, 0);
        }
        #pragma unroll
        for (int p = 0; p < 4; ++p) {
            int u = p * 256 + tid;
            int col = u & 127, c = u >> 7;
            const unsigned short* gb = B + (size_t)(bn + col) * K + k0 + c * 8;
            __builtin_amdgcn_global_load_lds(
                (const __attribute__((address_space(1))) unsigned int*)gb,
                (__attribute__((address_space(3))) unsigned int*)(&Bs[sel][u]), 16, 0, 0);
        }
    };
    auto compute = [&](int sel) {
        #pragma unroll
        for (int s = 0; s < 2; ++s) {
            const int cidx = s * 4 + (l >> 4);
            bf16x8 af[MI], bfr[4];
            #pragma unroll
            for (int mi = 0; mi < MI; ++mi) af[mi]  = As[sel][cidx * BM + wr + mi * 16 + (l & 15)];
            #pragma unroll
            for (int ni = 0; ni < 4; ++ni)  bfr[ni] = Bs[sel][cidx * 128 + wc + ni * 16 + (l & 15)];
            #pragma unroll
            for (int mi = 0; mi < MI; ++mi)
                #pragma unroll
                for (int ni = 0; ni < 4; ++ni)
                    acc[mi][ni] = __builtin_amdgcn_mfma_f32_16x16x32_bf16(
                        af[mi], bfr[ni], acc[mi][ni], 0, 0, 0);
        }
    };

    const int NT = K >> 6;               // even by contract
    stage(0, 0);
    __syncthreads();
    for (int t = 0; t < NT; t += 2) {
        stage((t + 1) << 6, 1);          // prefetch next tile (other buffer)
        compute(0);
        __syncthreads();                 // drains buf1 loads; buf0 now free
        if (t + 2 < NT) stage((t + 2) << 6, 0);
        compute(1);
        __syncthreads();
    }

    #pragma unroll
    for (int mi = 0; mi < MI; ++mi) {
        #pragma unroll
        for (int r = 0; r < 4; ++r) {
            const int row = bm + wr + mi * 16 + (l >> 4) * 4 + r;
            #pragma unroll
            for (int ni = 0; ni < 4; ++ni) {
                const int col = bn + wc + ni * 16 + (l & 15);
                if (col < N) {
                    float v = acc[mi][ni][r];
                    if (bias) v += bias[col];
                    if (GELU) v = 0.5f * v * (1.0f + erff(v * 0.70710678118654752f));
                    if (RES)  v += res[(size_t)row * N + col];
                    if (OUTF == 0) ((float*)Cout)[(size_t)row * N + col] = v;
                    else ((unsigned short*)Cout)[(size_t)row * N + col] = f2bf(v);
                }
            }
        }
    }
}

// ---------------- bf16 MFMA causal flash attention ----------------
__global__ __launch_bounds__(256)
void attn_mfma(const unsigned short* __restrict__ qkv, unsigned short* __restrict__ ao) {
    const int qt = gridDim.x - 1 - blockIdx.x;   // heavy blocks first
    const int h = blockIdx.y, b = blockIdx.z;
    const int tid = threadIdx.x;
    const int w = tid >> 6, l = tid & 63;
    const int c = l & 15, g = l >> 4;

    __shared__ unsigned short Ks[32 * 64];       // row-major, 16B-chunk XOR swizzle
    __shared__ unsigned short Vt[64 * 40];       // [d][krow], row pad 40 halves
    __shared__ unsigned int   Ps[4][16 * 20];    // per-wave P transpose

    const unsigned short* base = qkv + (size_t)(b * SEQ) * DQKV + h * HEAD;
    const int q0 = qt * 64 + w * 16;

    bf16x8 qf[2];
    {
        const unsigned short* qp = base + (size_t)(q0 + c) * DQKV + g * 8;
        qf[0] = *reinterpret_cast<const bf16x8*>(qp);
        qf[1] = *reinterpret_cast<const bf16x8*>(qp + 32);
    }

    f32x4 o_acc[4] = {};
    float m_run[4]  = {-INFINITY, -INFINITY, -INFINITY, -INFINITY};
    float l_run[4]  = {0.f, 0.f, 0.f, 0.f};

    const int srow = tid >> 3, schunk = tid & 7;
    const int vd = tid & 63, vw = tid >> 6;

    const int nkt = 2 * qt + 2;
    for (int kt = 0; kt < nkt; ++kt) {
        {
            const unsigned short* kp = base + (size_t)(kt * 32 + srow) * DQKV + 768 + schunk * 8;
            bf16x8 kv = *reinterpret_cast<const bf16x8*>(kp);
            *reinterpret_cast<bf16x8*>(&Ks[srow * 64 + ((schunk ^ (srow & 7)) * 8)]) = kv;
        }
        {
            unsigned short vv[8];
            #pragma unroll
            for (int j = 0; j < 8; ++j)
                vv[j] = base[(size_t)(kt * 32 + vw * 8 + j) * DQKV + 1536 + vd];
            uint4 pk;
            pk.x = vv[0] | ((unsigned)vv[1] << 16);
            pk.y = vv[2] | ((unsigned)vv[3] << 16);
            pk.z = vv[4] | ((unsigned)vv[5] << 16);
            pk.w = vv[6] | ((unsigned)vv[7] << 16);
            *reinterpret_cast<uint4*>(&Vt[vd * 40 + vw * 8]) = pk;
        }
        __syncthreads();

        f32x4 s_acc[2] = {};
        #pragma unroll
        for (int t = 0; t < 2; ++t) {
            const int kr = t * 16 + c;
            #pragma unroll
            for (int ks = 0; ks < 2; ++ks) {
                bf16x8 kf = *reinterpret_cast<const bf16x8*>(
                    &Ks[kr * 64 + (((ks * 4 + g) ^ (kr & 7)) * 8)]);
                s_acc[t] = __builtin_amdgcn_mfma_f32_16x16x32_bf16(qf[ks], kf, s_acc[t], 0, 0, 0);
            }
        }
        float sc[2][4];
        #pragma unroll
        for (int t = 0; t < 2; ++t) {
            const int kglob = kt * 32 + t * 16 + c;
            #pragma unroll
            for (int r = 0; r < 4; ++r) {
                float v = s_acc[t][r] * 0.125f;
                sc[t][r] = (kglob > q0 + g * 4 + r) ? -1e30f : v;
            }
        }
        float pout[2][4];
        #pragma unroll
        for (int r = 0; r < 4; ++r) {
            float tmax = fmaxf(sc[0][r], sc[1][r]);
            #pragma unroll
            for (int ms = 1; ms < 16; ms <<= 1) tmax = fmaxf(tmax, __shfl_xor(tmax, ms));
            float mnew = fmaxf(m_run[r], tmax);
            float alpha = __expf(m_run[r] - mnew);
            float p0 = __expf(sc[0][r] - mnew);
            float p1 = __expf(sc[1][r] - mnew);
            float psum = p0 + p1;
            #pragma unroll
            for (int ms = 1; ms < 16; ms <<= 1) psum += __shfl_xor(psum, ms);
            l_run[r] = l_run[r] * alpha + psum;
            m_run[r] = mnew;
            #pragma unroll
            for (int dt = 0; dt < 4; ++dt) o_acc[dt][r] *= alpha;
            pout[0][r] = p0; pout[1][r] = p1;
        }
        #pragma unroll
        for (int t = 0; t < 2; ++t) {
            #pragma unroll
            for (int r = 0; r < 4; ++r) {
                int my = f2bf(pout[t][r]);
                int part = __shfl_xor(my, 1);
                unsigned int word = (c & 1) ? ((unsigned)(part & 0xffff) | ((unsigned)my << 16))
                                            : ((unsigned)(my & 0xffff) | ((unsigned)part << 16));
                Ps[w][(g * 4 + r) * 20 + t * 8 + (c >> 1)] = word;
            }
        }
        uint4 praw = *reinterpret_cast<const uint4*>(&Ps[w][c * 20 + g * 4]);
        bf16x8 pf = *reinterpret_cast<const bf16x8*>(&praw);
        #pragma unroll
        for (int dt = 0; dt < 4; ++dt) {
            bf16x8 vf = *reinterpret_cast<const bf16x8*>(&Vt[(dt * 16 + c) * 40 + g * 8]);
            o_acc[dt] = __builtin_amdgcn_mfma_f32_16x16x32_bf16(pf, vf, o_acc[dt], 0, 0, 0);
        }
        __syncthreads();
    }

    float inv[4];
    #pragma unroll
    for (int r = 0; r < 4; ++r) inv[r] = 1.0f / l_run[r];
    #pragma unroll
    for (int r = 0; r < 4; ++r) {
        unsigned short* op = ao + (size_t)(b * SEQ + q0 + g * 4 + r) * D_MODEL + h * HEAD + c;
        #pragma unroll
        for (int dt = 0; dt < 4; ++dt)
            op[dt * 16] = f2bf(o_acc[dt][r] * inv[r]);
    }
}

extern "C" void kernel_launch(void* const* d_in, const int* in_sizes, int n_in,
                              void* d_out, int out_size, void* d_ws, size_t ws_size,
                              hipStream_t stream) {
    const int*   idx     = (const int*)  d_in[0];
    const float* tok_emb = (const float*)d_in[1];
    const float* pos_emb = (const float*)d_in[2];
    const float* Wq      = (const float*)d_in[3];
    const float* bq      = (const float*)d_in[4];
    const float* Wk      = (const float*)d_in[5];
    const float* bk      = (const float*)d_in[6];
    const float* Wv      = (const float*)d_in[7];
    const float* bv      = (const float*)d_in[8];
    const float* Wproj   = (const float*)d_in[9];
    const float* bproj   = (const float*)d_in[10];
    const float* ln1g    = (const float*)d_in[11];
    const float* ln1b    = (const float*)d_in[12];
    const float* ln2g    = (const float*)d_in[13];
    const float* ln2b    = (const float*)d_in[14];
    const float* Wf1     = (const float*)d_in[15];
    const float* bf1     = (const float*)d_in[16];
    const float* Wf2     = (const float*)d_in[17];
    const float* bf2     = (const float*)d_in[18];
    const float* lnfg    = (const float*)d_in[19];
    const float* lnfb    = (const float*)d_in[20];
    const float* Wlm     = (const float*)d_in[21];
    float* outp = (float*)d_out;

    char* basep = (char*)d_ws;
    size_t off = 0;
    auto alloc = [&](size_t bytes) -> void* {
        void* p = basep + off;
        off = (off + bytes + 255) & ~(size_t)255;
        return p;
    };
    float*          x      = (float*)         alloc((size_t)NROWS * D_MODEL * 4);
    unsigned short* qkv    = (unsigned short*)alloc((size_t)NROWS * DQKV * 2);
    unsigned short* hb     = (unsigned short*)alloc((size_t)NROWS * D_MODEL * 2);
    unsigned short* ao     = (unsigned short*)alloc((size_t)NROWS * D_MODEL * 2);
    unsigned short* mid    = (unsigned short*)alloc((size_t)NROWS * DFFN * 2);
    unsigned short* Wqkvb  = (unsigned short*)alloc((size_t)NLAYER * DQKV * D_MODEL * 2);
    unsigned short* Wprojb = (unsigned short*)alloc((size_t)NLAYER * D_MODEL * D_MODEL * 2);
    unsigned short* Wf1b   = (unsigned short*)alloc((size_t)NLAYER * DFFN * D_MODEL * 2);
    unsigned short* Wf2b   = (unsigned short*)alloc((size_t)NLAYER * D_MODEL * DFFN * 2);
    unsigned short* Wlmb   = (unsigned short*)alloc((size_t)VPAD * D_MODEL * 2);
    float*          bqkv   = (float*)         alloc((size_t)NLAYER * DQKV * 4);

    dim3 blk(256);
    dim3 tblk(32, 8);

    conv_lm<<<2048, blk, 0, stream>>>(Wlm, Wlmb);
    conv_transpose<1><<<dim3(24, 24, 6), tblk, 0, stream>>>(Wq, Wqkvb,             768, 768,  (size_t)768*768,  (size_t)DQKV*768);
    conv_transpose<1><<<dim3(24, 24, 6), tblk, 0, stream>>>(Wk, Wqkvb + 768*768,   768, 768,  (size_t)768*768,  (size_t)DQKV*768);
    conv_transpose<1><<<dim3(24, 24, 6), tblk, 0, stream>>>(Wv, Wqkvb + 2*768*768, 768, 768,  (size_t)768*768,  (size_t)DQKV*768);
    conv_transpose<0><<<dim3(24, 24, 6), tblk, 0, stream>>>(Wproj, Wprojb,         768, 768,  (size_t)768*768,  (size_t)768*768);
    conv_transpose<0><<<dim3(96, 24, 6), tblk, 0, stream>>>(Wf1, Wf1b,             768, 3072, (size_t)768*3072, (size_t)3072*768);
    conv_transpose<0><<<dim3(24, 96, 6), tblk, 0, stream>>>(Wf2, Wf2b,             3072, 768, (size_t)3072*768, (size_t)768*3072);
    conv_bias<<<(NLAYER * DQKV + 255) / 256, blk, 0, stream>>>(bq, bk, bv, bqkv);

    embed_kernel<<<NROWS, blk, 0, stream>>>(idx, tok_emb, pos_emb, x);

    dim3 gqkv(18 * 32);                  // BM=128
    dim3 g768s(6 * 64);                  // BM=64  (proj, FFN2)
    dim3 g3072(24 * 32);                 // BM=128
    dim3 ga(SEQ / 64, N_HEAD, BATCH);    // (16, 12, 4)

    for (int li = 0; li < NLAYER; ++li) {
        ln_kernel<<<NROWS, blk, 0, stream>>>(x, ln1g + li * D_MODEL, ln1b + li * D_MODEL, hb);

        gemm_mfma<128, 1, false, false><<<gqkv, blk, 0, stream>>>(
            hb, Wqkvb + (size_t)li * DQKV * D_MODEL, bqkv + li * DQKV, nullptr,
            qkv, NROWS, DQKV, D_MODEL);

        attn_mfma<<<ga, blk, 0, stream>>>(qkv, ao);

        gemm_mfma<64, 0, false, true><<<g768s, blk, 0, stream>>>(
            ao, Wprojb + (size_t)li * D_MODEL * D_MODEL, bproj + li * D_MODEL, x,
            x, NROWS, D_MODEL, D_MODEL);

        ln_kernel<<<NROWS, blk, 0, stream>>>(x, ln2g + li * D_MODEL, ln2b + li * D_MODEL, hb);

        gemm_mfma<128, 1, true, false><<<g3072, blk, 0, stream>>>(
            hb, Wf1b + (size_t)li * DFFN * D_MODEL, bf1 + li * DFFN, nullptr,
            mid, NROWS, DFFN, D_MODEL);

        gemm_mfma<64, 0, false, true><<<g768s, blk, 0, stream>>>(
            mid, Wf2b + (size_t)li * D_MODEL * DFFN, bf2 + li * D_MODEL, x,
            x, NROWS, D_MODEL, DFFN);
    }

    ln_kernel<<<NROWS, blk, 0, stream>>>(x, lnfg, lnfb, hb);

    dim3 gl(393 * 32);
    gemm_mfma<128, 0, false, false><<<gl, blk, 0, stream>>>(
        hb, Wlmb, nullptr, nullptr, outp, NROWS, VOCAB, D_MODEL);
}

// Round 6
// 3123.620 us; speedup vs baseline: 1.0181x; 1.0181x over previous
//
#include <hip/hip_runtime.h>
#include <hip/hip_bf16.h>
#include <math.h>

#define D_MODEL 768
#define N_HEAD  12
#define HEAD    64
#define SEQ     1024
#define NLAYER  6
#define BATCH   4
#define NROWS   (BATCH*SEQ)   // 4096
#define VOCAB   50257
#define VPAD    50304         // 393*128
#define DFFN    3072
#define DQKV    2304

typedef __attribute__((ext_vector_type(8))) __bf16 bf16x8;
typedef __attribute__((ext_vector_type(4))) float f32x4;
typedef __attribute__((ext_vector_type(4))) unsigned short u16x4;

__device__ inline unsigned short f2bf(float x) {
    __hip_bfloat16 h = __float2bfloat16(x);
    return *reinterpret_cast<unsigned short*>(&h);
}

// ---------------- embedding ----------------
__global__ __launch_bounds__(256)
void embed_kernel(const int* __restrict__ idx, const float* __restrict__ tok,
                  const float* __restrict__ pos, float* __restrict__ x) {
    int row = blockIdx.x;
    int t = idx[row];
    int s = row & (SEQ - 1);
    const float* tp = tok + (size_t)t * D_MODEL;
    const float* pp = pos + (size_t)s * D_MODEL;
    float* xp = x + (size_t)row * D_MODEL;
    for (int i = threadIdx.x; i < D_MODEL; i += 256) xp[i] = tp[i] + pp[i];
}

// ---------------- layernorm: fp32 in, bf16 out ----------------
__global__ __launch_bounds__(256)
void ln_kernel(const float* __restrict__ in, const float* __restrict__ gw,
               const float* __restrict__ bw, unsigned short* __restrict__ out) {
    int row = blockIdx.x;
    int tid = threadIdx.x;
    const float* x = in + (size_t)row * D_MODEL;
    float v0 = x[tid], v1 = x[tid + 256], v2 = x[tid + 512];
    float s  = v0 + v1 + v2;
    float sq = v0*v0 + v1*v1 + v2*v2;
    #pragma unroll
    for (int o = 1; o < 64; o <<= 1) { s += __shfl_xor(s, o); sq += __shfl_xor(sq, o); }
    __shared__ float red[8];
    int wave = tid >> 6;
    if ((tid & 63) == 0) { red[wave] = s; red[4 + wave] = sq; }
    __syncthreads();
    s  = red[0] + red[1] + red[2] + red[3];
    sq = red[4] + red[5] + red[6] + red[7];
    float mean = s * (1.0f / D_MODEL);
    float var  = sq * (1.0f / D_MODEL) - mean * mean;
    float rstd = rsqrtf(var + 1e-5f);
    unsigned short* op = out + (size_t)row * D_MODEL;
    op[tid]       = f2bf((v0 - mean) * rstd * gw[tid]       + bw[tid]);
    op[tid + 256] = f2bf((v1 - mean) * rstd * gw[tid + 256] + bw[tid + 256]);
    op[tid + 512] = f2bf((v2 - mean) * rstd * gw[tid + 512] + bw[tid + 512]);
}

// ---------------- weight conversion ----------------
template<int MODE>
__global__ __launch_bounds__(256)
void conv_transpose(const float* __restrict__ in, unsigned short* __restrict__ out,
                    int K, int N, size_t inLstride, size_t outLstride) {
    __shared__ float t[32][33];
    const int tx = threadIdx.x, ty = threadIdx.y;
    const int n0 = blockIdx.x * 32, k0 = blockIdx.y * 32;
    const float* ip = in + blockIdx.z * inLstride;
    unsigned short* op = out + blockIdx.z * outLstride;
    #pragma unroll
    for (int j = 0; j < 4; ++j) {
        int k = k0 + ty + j * 8, n = n0 + tx;
        float v = (MODE == 0) ? ip[(size_t)k * N + n]
                              : ip[(size_t)((n >> 6) * K + k) * 64 + (n & 63)];
        t[ty + j * 8][tx] = v;
    }
    __syncthreads();
    #pragma unroll
    for (int j = 0; j < 4; ++j) {
        int n = n0 + ty + j * 8, k = k0 + tx;
        op[(size_t)n * K + k] = f2bf(t[tx][ty + j * 8]);
    }
}

__global__ __launch_bounds__(256)
void conv_lm(const float* __restrict__ in, unsigned short* __restrict__ out) {
    const int nchunks = VPAD * D_MODEL / 4;
    const int vchunks = VOCAB * D_MODEL / 4;
    for (int i = blockIdx.x * 256 + threadIdx.x; i < nchunks; i += gridDim.x * 256) {
        u16x4 o;
        if (i < vchunks) {
            float4 v = reinterpret_cast<const float4*>(in)[i];
            o[0] = f2bf(v.x); o[1] = f2bf(v.y); o[2] = f2bf(v.z); o[3] = f2bf(v.w);
        } else { o[0] = 0; o[1] = 0; o[2] = 0; o[3] = 0; }
        reinterpret_cast<u16x4*>(out)[i] = o;
    }
}

__global__ __launch_bounds__(256)
void conv_bias(const float* __restrict__ bq, const float* __restrict__ bk,
               const float* __restrict__ bv, float* __restrict__ out) {
    int i = blockIdx.x * 256 + threadIdx.x;
    if (i >= NLAYER * DQKV) return;
    int l = i / DQKV, n = i % DQKV;
    float v;
    if (n < 768)        v = bq[l * 768 + n];
    else if (n < 1536)  v = bk[l * 768 + n - 768];
    else                v = bv[l * 768 + n - 1536];
    out[i] = v;
}

// ---------------- bf16 MFMA GEMM, 2-deep counted-vmcnt pipeline (T4) ----------------
// C[M,N] = A[M,K](bf16) @ B[N,K](bf16)^T + bias (+GELU) (+res)
// 1D grid, nwg = (M/BM)*(N/128), nwg%8==0, (M/BM)%8==0, (K/64) even.
// Raw s_barrier + counted s_waitcnt vmcnt(SPW): two stages stay in flight, so
// each buffer's data is awaited two full compute phases after issue.
template<int BM, int OUTF /*0=f32,1=bf16*/, bool GELU, bool RES>
__global__ __launch_bounds__(256)
void gemm_mfma(const unsigned short* __restrict__ A, const unsigned short* __restrict__ B,
               const float* __restrict__ bias, const float* __restrict__ res,
               void* __restrict__ Cout, int M, int N, int K) {
    constexpr int ACH = BM * 8;          // bf16x8 chunks per A tile
    __shared__ bf16x8 As[2][ACH];
    __shared__ bf16x8 Bs[2][1024];
    // XCD-contiguous chunks; by fastest within groups of 8 rows, bx slow.
    const int nwg = gridDim.x;
    const int t0 = (blockIdx.x & 7) * (nwg >> 3) + (blockIdx.x >> 3);
    const int MT = M / BM;
    const int NBX = nwg / MT;
    const int srsize = NBX * 8;
    const int sr = t0 / srsize;
    const int rem = t0 - sr * srsize;
    const int bx = rem >> 3;
    const int by = sr * 8 + (rem & 7);
    const int bm = by * BM, bn = bx * 128;
    const int tid = threadIdx.x;
    const int l = tid & 63, w = tid >> 6;
    constexpr int MI = (BM == 128) ? 4 : 2;
    const int wr = (BM == 128) ? (w >> 1) * 64 : (w & 1) * 32;
    const int wc = (BM == 128) ? (w & 1) * 64 : (w >> 1) * 64;
    f32x4 acc[MI][4] = {};

    auto stage = [&](int k0, int sel) {
        #pragma unroll
        for (int p = 0; p < ACH / 256; ++p) {
            int u = p * 256 + tid;
            int row = u % BM, c = u / BM;
            const unsigned short* ga = A + (size_t)(bm + row) * K + k0 + c * 8;
            __builtin_amdgcn_global_load_lds(
                (const __attribute__((address_space(1))) unsigned int*)ga,
                (__attribute__((address_space(3))) unsigned int*)(&As[sel][u]), 16, 0, 0);
        }
        #pragma unroll
        for (int p = 0; p < 4; ++p) {
            int u = p * 256 + tid;
            int col = u & 127, c = u >> 7;
            const unsigned short* gb = B + (size_t)(bn + col) * K + k0 + c * 8;
            __builtin_amdgcn_global_load_lds(
                (const __attribute__((address_space(1))) unsigned int*)gb,
                (__attribute__((address_space(3))) unsigned int*)(&Bs[sel][u]), 16, 0, 0);
        }
    };
    auto compute = [&](int sel) {
        #pragma unroll
        for (int s = 0; s < 2; ++s) {
            const int cidx = s * 4 + (l >> 4);
            bf16x8 af[MI], bfr[4];
            #pragma unroll
            for (int mi = 0; mi < MI; ++mi) af[mi]  = As[sel][cidx * BM + wr + mi * 16 + (l & 15)];
            #pragma unroll
            for (int ni = 0; ni < 4; ++ni)  bfr[ni] = Bs[sel][cidx * 128 + wc + ni * 16 + (l & 15)];
            #pragma unroll
            for (int mi = 0; mi < MI; ++mi)
                #pragma unroll
                for (int ni = 0; ni < 4; ++ni)
                    acc[mi][ni] = __builtin_amdgcn_mfma_f32_16x16x32_bf16(
                        af[mi], bfr[ni], acc[mi][ni], 0, 0, 0);
        }
    };
    // counted wait: leave the newest stage (SPW wave-instructions) in flight
    auto waitvm_spw = [&]() {
        if constexpr (BM == 128) asm volatile("s_waitcnt vmcnt(8)" ::: "memory");
        else                     asm volatile("s_waitcnt vmcnt(6)" ::: "memory");
    };
    auto waitvm0  = [&]() { asm volatile("s_waitcnt vmcnt(0)" ::: "memory"); };
    auto waitlgkm = [&]() { asm volatile("s_waitcnt lgkmcnt(0)" ::: "memory"); };
    auto bar      = [&]() { __builtin_amdgcn_s_barrier(); };

    const int NT = K >> 6;               // even by contract, >= 2
    stage(0, 0);
    stage(64, 1);
    waitvm_spw();                        // tile0 landed (tile1 still in flight)
    bar();
    for (int t = 0; t < NT; t += 2) {
        compute(0);                      // tile t
        waitlgkm(); bar();               // all waves done reading buf0
        if (t + 2 < NT) { stage((t + 2) << 6, 0); waitvm_spw(); }
        else            { waitvm0(); }
        bar();                           // buf1 (tile t+1) visible everywhere
        compute(1);                      // tile t+1
        waitlgkm(); bar();               // all waves done reading buf1
        if (t + 3 < NT) { stage((t + 3) << 6, 1); waitvm_spw(); }
        else            { waitvm0(); }
        bar();                           // buf0 (tile t+2) visible everywhere
    }

    #pragma unroll
    for (int mi = 0; mi < MI; ++mi) {
        #pragma unroll
        for (int r = 0; r < 4; ++r) {
            const int row = bm + wr + mi * 16 + (l >> 4) * 4 + r;
            #pragma unroll
            for (int ni = 0; ni < 4; ++ni) {
                const int col = bn + wc + ni * 16 + (l & 15);
                if (col < N) {
                    float v = acc[mi][ni][r];
                    if (bias) v += bias[col];
                    if (GELU) v = 0.5f * v * (1.0f + erff(v * 0.70710678118654752f));
                    if (RES)  v += res[(size_t)row * N + col];
                    if (OUTF == 0) ((float*)Cout)[(size_t)row * N + col] = v;
                    else ((unsigned short*)Cout)[(size_t)row * N + col] = f2bf(v);
                }
            }
        }
    }
}

// ---------------- bf16 MFMA causal flash attention ----------------
__global__ __launch_bounds__(256)
void attn_mfma(const unsigned short* __restrict__ qkv, unsigned short* __restrict__ ao) {
    const int qt = gridDim.x - 1 - blockIdx.x;   // heavy blocks first
    const int h = blockIdx.y, b = blockIdx.z;
    const int tid = threadIdx.x;
    const int w = tid >> 6, l = tid & 63;
    const int c = l & 15, g = l >> 4;

    __shared__ unsigned short Ks[32 * 64];       // row-major, 16B-chunk XOR swizzle
    __shared__ unsigned short Vt[64 * 40];       // [d][krow], row pad 40 halves
    __shared__ unsigned int   Ps[4][16 * 20];    // per-wave P transpose

    const unsigned short* base = qkv + (size_t)(b * SEQ) * DQKV + h * HEAD;
    const int q0 = qt * 64 + w * 16;

    bf16x8 qf[2];
    {
        const unsigned short* qp = base + (size_t)(q0 + c) * DQKV + g * 8;
        qf[0] = *reinterpret_cast<const bf16x8*>(qp);
        qf[1] = *reinterpret_cast<const bf16x8*>(qp + 32);
    }

    f32x4 o_acc[4] = {};
    float m_run[4]  = {-INFINITY, -INFINITY, -INFINITY, -INFINITY};
    float l_run[4]  = {0.f, 0.f, 0.f, 0.f};

    const int srow = tid >> 3, schunk = tid & 7;
    const int vd = tid & 63, vw = tid >> 6;

    const int nkt = 2 * qt + 2;
    for (int kt = 0; kt < nkt; ++kt) {
        {
            const unsigned short* kp = base + (size_t)(kt * 32 + srow) * DQKV + 768 + schunk * 8;
            bf16x8 kv = *reinterpret_cast<const bf16x8*>(kp);
            *reinterpret_cast<bf16x8*>(&Ks[srow * 64 + ((schunk ^ (srow & 7)) * 8)]) = kv;
        }
        {
            unsigned short vv[8];
            #pragma unroll
            for (int j = 0; j < 8; ++j)
                vv[j] = base[(size_t)(kt * 32 + vw * 8 + j) * DQKV + 1536 + vd];
            uint4 pk;
            pk.x = vv[0] | ((unsigned)vv[1] << 16);
            pk.y = vv[2] | ((unsigned)vv[3] << 16);
            pk.z = vv[4] | ((unsigned)vv[5] << 16);
            pk.w = vv[6] | ((unsigned)vv[7] << 16);
            *reinterpret_cast<uint4*>(&Vt[vd * 40 + vw * 8]) = pk;
        }
        __syncthreads();

        f32x4 s_acc[2] = {};
        #pragma unroll
        for (int t = 0; t < 2; ++t) {
            const int kr = t * 16 + c;
            #pragma unroll
            for (int ks = 0; ks < 2; ++ks) {
                bf16x8 kf = *reinterpret_cast<const bf16x8*>(
                    &Ks[kr * 64 + (((ks * 4 + g) ^ (kr & 7)) * 8)]);
                s_acc[t] = __builtin_amdgcn_mfma_f32_16x16x32_bf16(qf[ks], kf, s_acc[t], 0, 0, 0);
            }
        }
        float sc[2][4];
        #pragma unroll
        for (int t = 0; t < 2; ++t) {
            const int kglob = kt * 32 + t * 16 + c;
            #pragma unroll
            for (int r = 0; r < 4; ++r) {
                float v = s_acc[t][r] * 0.125f;
                sc[t][r] = (kglob > q0 + g * 4 + r) ? -1e30f : v;
            }
        }
        float pout[2][4];
        #pragma unroll
        for (int r = 0; r < 4; ++r) {
            float tmax = fmaxf(sc[0][r], sc[1][r]);
            #pragma unroll
            for (int ms = 1; ms < 16; ms <<= 1) tmax = fmaxf(tmax, __shfl_xor(tmax, ms));
            float mnew = fmaxf(m_run[r], tmax);
            float alpha = __expf(m_run[r] - mnew);
            float p0 = __expf(sc[0][r] - mnew);
            float p1 = __expf(sc[1][r] - mnew);
            float psum = p0 + p1;
            #pragma unroll
            for (int ms = 1; ms < 16; ms <<= 1) psum += __shfl_xor(psum, ms);
            l_run[r] = l_run[r] * alpha + psum;
            m_run[r] = mnew;
            #pragma unroll
            for (int dt = 0; dt < 4; ++dt) o_acc[dt][r] *= alpha;
            pout[0][r] = p0; pout[1][r] = p1;
        }
        #pragma unroll
        for (int t = 0; t < 2; ++t) {
            #pragma unroll
            for (int r = 0; r < 4; ++r) {
                int my = f2bf(pout[t][r]);
                int part = __shfl_xor(my, 1);
                unsigned int word = (c & 1) ? ((unsigned)(part & 0xffff) | ((unsigned)my << 16))
                                            : ((unsigned)(my & 0xffff) | ((unsigned)part << 16));
                Ps[w][(g * 4 + r) * 20 + t * 8 + (c >> 1)] = word;
            }
        }
        uint4 praw = *reinterpret_cast<const uint4*>(&Ps[w][c * 20 + g * 4]);
        bf16x8 pf = *reinterpret_cast<const bf16x8*>(&praw);
        #pragma unroll
        for (int dt = 0; dt < 4; ++dt) {
            bf16x8 vf = *reinterpret_cast<const bf16x8*>(&Vt[(dt * 16 + c) * 40 + g * 8]);
            o_acc[dt] = __builtin_amdgcn_mfma_f32_16x16x32_bf16(pf, vf, o_acc[dt], 0, 0, 0);
        }
        __syncthreads();
    }

    float inv[4];
    #pragma unroll
    for (int r = 0; r < 4; ++r) inv[r] = 1.0f / l_run[r];
    #pragma unroll
    for (int r = 0; r < 4; ++r) {
        unsigned short* op = ao + (size_t)(b * SEQ + q0 + g * 4 + r) * D_MODEL + h * HEAD + c;
        #pragma unroll
        for (int dt = 0; dt < 4; ++dt)
            op[dt * 16] = f2bf(o_acc[dt][r] * inv[r]);
    }
}

extern "C" void kernel_launch(void* const* d_in, const int* in_sizes, int n_in,
                              void* d_out, int out_size, void* d_ws, size_t ws_size,
                              hipStream_t stream) {
    const int*   idx     = (const int*)  d_in[0];
    const float* tok_emb = (const float*)d_in[1];
    const float* pos_emb = (const float*)d_in[2];
    const float* Wq      = (const float*)d_in[3];
    const float* bq      = (const float*)d_in[4];
    const float* Wk      = (const float*)d_in[5];
    const float* bk      = (const float*)d_in[6];
    const float* Wv      = (const float*)d_in[7];
    const float* bv      = (const float*)d_in[8];
    const float* Wproj   = (const float*)d_in[9];
    const float* bproj   = (const float*)d_in[10];
    const float* ln1g    = (const float*)d_in[11];
    const float* ln1b    = (const float*)d_in[12];
    const float* ln2g    = (const float*)d_in[13];
    const float* ln2b    = (const float*)d_in[14];
    const float* Wf1     = (const float*)d_in[15];
    const float* bf1     = (const float*)d_in[16];
    const float* Wf2     = (const float*)d_in[17];
    const float* bf2     = (const float*)d_in[18];
    const float* lnfg    = (const float*)d_in[19];
    const float* lnfb    = (const float*)d_in[20];
    const float* Wlm     = (const float*)d_in[21];
    float* outp = (float*)d_out;

    char* basep = (char*)d_ws;
    size_t off = 0;
    auto alloc = [&](size_t bytes) -> void* {
        void* p = basep + off;
        off = (off + bytes + 255) & ~(size_t)255;
        return p;
    };
    float*          x      = (float*)         alloc((size_t)NROWS * D_MODEL * 4);
    unsigned short* qkv    = (unsigned short*)alloc((size_t)NROWS * DQKV * 2);
    unsigned short* hb     = (unsigned short*)alloc((size_t)NROWS * D_MODEL * 2);
    unsigned short* ao     = (unsigned short*)alloc((size_t)NROWS * D_MODEL * 2);
    unsigned short* mid    = (unsigned short*)alloc((size_t)NROWS * DFFN * 2);
    unsigned short* Wqkvb  = (unsigned short*)alloc((size_t)NLAYER * DQKV * D_MODEL * 2);
    unsigned short* Wprojb = (unsigned short*)alloc((size_t)NLAYER * D_MODEL * D_MODEL * 2);
    unsigned short* Wf1b   = (unsigned short*)alloc((size_t)NLAYER * DFFN * D_MODEL * 2);
    unsigned short* Wf2b   = (unsigned short*)alloc((size_t)NLAYER * D_MODEL * DFFN * 2);
    unsigned short* Wlmb   = (unsigned short*)alloc((size_t)VPAD * D_MODEL * 2);
    float*          bqkv   = (float*)         alloc((size_t)NLAYER * DQKV * 4);

    dim3 blk(256);
    dim3 tblk(32, 8);

    conv_lm<<<2048, blk, 0, stream>>>(Wlm, Wlmb);
    conv_transpose<1><<<dim3(24, 24, 6), tblk, 0, stream>>>(Wq, Wqkvb,             768, 768,  (size_t)768*768,  (size_t)DQKV*768);
    conv_transpose<1><<<dim3(24, 24, 6), tblk, 0, stream>>>(Wk, Wqkvb + 768*768,   768, 768,  (size_t)768*768,  (size_t)DQKV*768);
    conv_transpose<1><<<dim3(24, 24, 6), tblk, 0, stream>>>(Wv, Wqkvb + 2*768*768, 768, 768,  (size_t)768*768,  (size_t)DQKV*768);
    conv_transpose<0><<<dim3(24, 24, 6), tblk, 0, stream>>>(Wproj, Wprojb,         768, 768,  (size_t)768*768,  (size_t)768*768);
    conv_transpose<0><<<dim3(96, 24, 6), tblk, 0, stream>>>(Wf1, Wf1b,             768, 3072, (size_t)768*3072, (size_t)3072*768);
    conv_transpose<0><<<dim3(24, 96, 6), tblk, 0, stream>>>(Wf2, Wf2b,             3072, 768, (size_t)3072*768, (size_t)768*3072);
    conv_bias<<<(NLAYER * DQKV + 255) / 256, blk, 0, stream>>>(bq, bk, bv, bqkv);

    embed_kernel<<<NROWS, blk, 0, stream>>>(idx, tok_emb, pos_emb, x);

    dim3 gqkv(18 * 32);                  // BM=128
    dim3 g768s(6 * 64);                  // BM=64  (proj, FFN2)
    dim3 g3072(24 * 32);                 // BM=128
    dim3 ga(SEQ / 64, N_HEAD, BATCH);    // (16, 12, 4)

    for (int li = 0; li < NLAYER; ++li) {
        ln_kernel<<<NROWS, blk, 0, stream>>>(x, ln1g + li * D_MODEL, ln1b + li * D_MODEL, hb);

        gemm_mfma<128, 1, false, false><<<gqkv, blk, 0, stream>>>(
            hb, Wqkvb + (size_t)li * DQKV * D_MODEL, bqkv + li * DQKV, nullptr,
            qkv, NROWS, DQKV, D_MODEL);

        attn_mfma<<<ga, blk, 0, stream>>>(qkv, ao);

        gemm_mfma<64, 0, false, true><<<g768s, blk, 0, stream>>>(
            ao, Wprojb + (size_t)li * D_MODEL * D_MODEL, bproj + li * D_MODEL, x,
            x, NROWS, D_MODEL, D_MODEL);

        ln_kernel<<<NROWS, blk, 0, stream>>>(x, ln2g + li * D_MODEL, ln2b + li * D_MODEL, hb);

        gemm_mfma<128, 1, true, false><<<g3072, blk, 0, stream>>>(
            hb, Wf1b + (size_t)li * DFFN * D_MODEL, bf1 + li * DFFN, nullptr,
            mid, NROWS, DFFN, D_MODEL);

        gemm_mfma<64, 0, false, true><<<g768s, blk, 0, stream>>>(
            mid, Wf2b + (size_t)li * D_MODEL * DFFN, bf2 + li * D_MODEL, x,
            x, NROWS, D_MODEL, DFFN);
    }

    ln_kernel<<<NROWS, blk, 0, stream>>>(x, lnfg, lnfb, hb);

    dim3 gl(393 * 32);
    gemm_mfma<128, 0, false, false><<<gl, blk, 0, stream>>>(
        hb, Wlmb, nullptr, nullptr, outp, NROWS, VOCAB, D_MODEL);
}

// Round 7
// 2764.115 us; speedup vs baseline: 1.1505x; 1.1301x over previous
//
#include <hip/hip_runtime.h>
#include <hip/hip_bf16.h>
#include <math.h>

#define D_MODEL 768
#define N_HEAD  12
#define HEAD    64
#define SEQ     1024
#define NLAYER  6
#define BATCH   4
#define NROWS   (BATCH*SEQ)   // 4096
#define VOCAB   50257
#define VPAD    50432         // 197*256
#define DFFN    3072
#define DQKV    2304

typedef __attribute__((ext_vector_type(8))) __bf16 bf16x8;
typedef __attribute__((ext_vector_type(4))) float f32x4;
typedef __attribute__((ext_vector_type(4))) unsigned short u16x4;

__device__ inline unsigned short f2bf(float x) {
    __hip_bfloat16 h = __float2bfloat16(x);
    return *reinterpret_cast<unsigned short*>(&h);
}

// ---------------- embedding ----------------
__global__ __launch_bounds__(256)
void embed_kernel(const int* __restrict__ idx, const float* __restrict__ tok,
                  const float* __restrict__ pos, float* __restrict__ x) {
    int row = blockIdx.x;
    int t = idx[row];
    int s = row & (SEQ - 1);
    const float* tp = tok + (size_t)t * D_MODEL;
    const float* pp = pos + (size_t)s * D_MODEL;
    float* xp = x + (size_t)row * D_MODEL;
    for (int i = threadIdx.x; i < D_MODEL; i += 256) xp[i] = tp[i] + pp[i];
}

// ---------------- layernorm: fp32 in, bf16 out ----------------
__global__ __launch_bounds__(256)
void ln_kernel(const float* __restrict__ in, const float* __restrict__ gw,
               const float* __restrict__ bw, unsigned short* __restrict__ out) {
    int row = blockIdx.x;
    int tid = threadIdx.x;
    const float* x = in + (size_t)row * D_MODEL;
    float v0 = x[tid], v1 = x[tid + 256], v2 = x[tid + 512];
    float s  = v0 + v1 + v2;
    float sq = v0*v0 + v1*v1 + v2*v2;
    #pragma unroll
    for (int o = 1; o < 64; o <<= 1) { s += __shfl_xor(s, o); sq += __shfl_xor(sq, o); }
    __shared__ float red[8];
    int wave = tid >> 6;
    if ((tid & 63) == 0) { red[wave] = s; red[4 + wave] = sq; }
    __syncthreads();
    s  = red[0] + red[1] + red[2] + red[3];
    sq = red[4] + red[5] + red[6] + red[7];
    float mean = s * (1.0f / D_MODEL);
    float var  = sq * (1.0f / D_MODEL) - mean * mean;
    float rstd = rsqrtf(var + 1e-5f);
    unsigned short* op = out + (size_t)row * D_MODEL;
    op[tid]       = f2bf((v0 - mean) * rstd * gw[tid]       + bw[tid]);
    op[tid + 256] = f2bf((v1 - mean) * rstd * gw[tid + 256] + bw[tid + 256]);
    op[tid + 512] = f2bf((v2 - mean) * rstd * gw[tid + 512] + bw[tid + 512]);
}

// ---------------- weight conversion ----------------
template<int MODE>
__global__ __launch_bounds__(256)
void conv_transpose(const float* __restrict__ in, unsigned short* __restrict__ out,
                    int K, int N, size_t inLstride, size_t outLstride) {
    __shared__ float t[32][33];
    const int tx = threadIdx.x, ty = threadIdx.y;
    const int n0 = blockIdx.x * 32, k0 = blockIdx.y * 32;
    const float* ip = in + blockIdx.z * inLstride;
    unsigned short* op = out + blockIdx.z * outLstride;
    #pragma unroll
    for (int j = 0; j < 4; ++j) {
        int k = k0 + ty + j * 8, n = n0 + tx;
        float v = (MODE == 0) ? ip[(size_t)k * N + n]
                              : ip[(size_t)((n >> 6) * K + k) * 64 + (n & 63)];
        t[ty + j * 8][tx] = v;
    }
    __syncthreads();
    #pragma unroll
    for (int j = 0; j < 4; ++j) {
        int n = n0 + ty + j * 8, k = k0 + tx;
        op[(size_t)n * K + k] = f2bf(t[tx][ty + j * 8]);
    }
}

__global__ __launch_bounds__(256)
void conv_lm(const float* __restrict__ in, unsigned short* __restrict__ out) {
    const int nchunks = VPAD * D_MODEL / 4;
    const int vchunks = VOCAB * D_MODEL / 4;
    for (int i = blockIdx.x * 256 + threadIdx.x; i < nchunks; i += gridDim.x * 256) {
        u16x4 o;
        if (i < vchunks) {
            float4 v = reinterpret_cast<const float4*>(in)[i];
            o[0] = f2bf(v.x); o[1] = f2bf(v.y); o[2] = f2bf(v.z); o[3] = f2bf(v.w);
        } else { o[0] = 0; o[1] = 0; o[2] = 0; o[3] = 0; }
        reinterpret_cast<u16x4*>(out)[i] = o;
    }
}

__global__ __launch_bounds__(256)
void conv_bias(const float* __restrict__ bq, const float* __restrict__ bk,
               const float* __restrict__ bv, float* __restrict__ out) {
    int i = blockIdx.x * 256 + threadIdx.x;
    if (i >= NLAYER * DQKV) return;
    int l = i / DQKV, n = i % DQKV;
    float v;
    if (n < 768)        v = bq[l * 768 + n];
    else if (n < 1536)  v = bk[l * 768 + n - 768];
    else                v = bv[l * 768 + n - 1536];
    out[i] = v;
}

// ---------------- 256x256 bf16 MFMA GEMM (logits) ----------------
// C[M,N] = A[M,K] @ B[N,K]^T, fp32 out. 512 threads = 8 waves (2M x 4N).
// LDS: 2 buffers x (A 256x64 + B 256x64) bf16, row-major with chunk^=(row&7)
// swizzle (applied on pre-swizzled global source AND on ds_read — rule #21).
// Schedule: issue ALL staging for tile t+1 at top of tile t; vmcnt(0)+barrier
// after compute(t) -> drain lands ~1300cyc after issue > HBM latency.
__global__ __launch_bounds__(512)
void gemm256_mfma(const unsigned short* __restrict__ A, const unsigned short* __restrict__ B,
                  float* __restrict__ C, int M, int N, int K) {
    __shared__ unsigned short smem[2 * 2 * 16384];   // 128 KiB
    const int nwg = gridDim.x;
    const int t0 = (blockIdx.x & 7) * (nwg >> 3) + (blockIdx.x >> 3);
    const int MT = M >> 8;
    const int NBX = nwg / MT;
    const int srsize = NBX * 8;
    const int sr = t0 / srsize;
    const int rem = t0 - sr * srsize;
    const int bx = rem >> 3;
    const int by = sr * 8 + (rem & 7);
    const int bm = by * 256, bn = bx * 256;
    const int tid = threadIdx.x;
    const int l = tid & 63, w = tid >> 6;
    const int wm = w >> 2, wn = w & 3;
    const int lr = l & 15, lc = l >> 4;
    f32x4 acc[8][4] = {};

    auto stage = [&](int k0, int buf) {
        #pragma unroll
        for (int p = 0; p < 4; ++p) {
            int d16 = p * 512 + tid;
            int row = d16 >> 3, cph = d16 & 7;
            int clog = cph ^ (row & 7);
            const unsigned short* ga = A + (size_t)(bm + row) * K + k0 + clog * 8;
            __builtin_amdgcn_global_load_lds(
                (const __attribute__((address_space(1))) unsigned int*)ga,
                (__attribute__((address_space(3))) unsigned int*)(&smem[buf * 32768 + d16 * 8]), 16, 0, 0);
        }
        #pragma unroll
        for (int p = 0; p < 4; ++p) {
            int d16 = p * 512 + tid;
            int row = d16 >> 3, cph = d16 & 7;
            int clog = cph ^ (row & 7);
            const unsigned short* gb = B + (size_t)(bn + row) * K + k0 + clog * 8;
            __builtin_amdgcn_global_load_lds(
                (const __attribute__((address_space(1))) unsigned int*)gb,
                (__attribute__((address_space(3))) unsigned int*)(&smem[buf * 32768 + 16384 + d16 * 8]), 16, 0, 0);
        }
    };

    auto compute = [&](int buf) {
        const unsigned short* Ab = &smem[buf * 32768];
        const unsigned short* Bb = &smem[buf * 32768 + 16384];
        #pragma unroll
        for (int qm = 0; qm < 2; ++qm) {
            bf16x8 af[2][4];
            #pragma unroll
            for (int ks = 0; ks < 2; ++ks)
                #pragma unroll
                for (int mi = 0; mi < 4; ++mi) {
                    int row = wm * 128 + qm * 64 + mi * 16 + lr;
                    af[ks][mi] = *reinterpret_cast<const bf16x8*>(
                        &Ab[row * 64 + (((ks * 4 + lc) ^ (row & 7)) * 8)]);
                }
            #pragma unroll
            for (int qn = 0; qn < 2; ++qn) {
                bf16x8 bfr[2][2];
                #pragma unroll
                for (int ks = 0; ks < 2; ++ks)
                    #pragma unroll
                    for (int ni = 0; ni < 2; ++ni) {
                        int col = wn * 64 + qn * 32 + ni * 16 + lr;
                        bfr[ks][ni] = *reinterpret_cast<const bf16x8*>(
                            &Bb[col * 64 + (((ks * 4 + lc) ^ (col & 7)) * 8)]);
                    }
                __builtin_amdgcn_s_setprio(1);
                #pragma unroll
                for (int ks = 0; ks < 2; ++ks)
                    #pragma unroll
                    for (int mi = 0; mi < 4; ++mi)
                        #pragma unroll
                        for (int ni = 0; ni < 2; ++ni)
                            acc[qm * 4 + mi][qn * 2 + ni] = __builtin_amdgcn_mfma_f32_16x16x32_bf16(
                                af[ks][mi], bfr[ks][ni], acc[qm * 4 + mi][qn * 2 + ni], 0, 0, 0);
                __builtin_amdgcn_s_setprio(0);
            }
        }
    };

    const int NT = K >> 6;
    stage(0, 0);
    asm volatile("s_waitcnt vmcnt(0)" ::: "memory");
    __builtin_amdgcn_s_barrier();
    for (int t = 0; t < NT; ++t) {
        const int cur = t & 1;
        if (t + 1 < NT) stage((t + 1) << 6, cur ^ 1);   // issue-early into freed buffer
        compute(cur);
        if (t + 1 < NT) {
            asm volatile("s_waitcnt vmcnt(0)" ::: "memory");  // t+1 landed (~full tile of coverage)
            __builtin_amdgcn_s_barrier();
        }
    }

    #pragma unroll
    for (int i = 0; i < 8; ++i) {          // i = qm*4+mi -> row block i*16
        #pragma unroll
        for (int r = 0; r < 4; ++r) {
            const int row = bm + wm * 128 + i * 16 + lc * 4 + r;
            #pragma unroll
            for (int j = 0; j < 4; ++j) {  // j = qn*2+ni -> col block j*16
                const int col = bn + wn * 64 + j * 16 + lr;
                if (col < N) C[(size_t)row * N + col] = acc[i][j][r];
            }
        }
    }
}

// ---------------- bf16 MFMA GEMM (layer GEMMs), 2-deep counted-vmcnt ----------------
template<int BM, int OUTF /*0=f32,1=bf16*/, bool GELU, bool RES>
__global__ __launch_bounds__(256)
void gemm_mfma(const unsigned short* __restrict__ A, const unsigned short* __restrict__ B,
               const float* __restrict__ bias, const float* __restrict__ res,
               void* __restrict__ Cout, int M, int N, int K) {
    constexpr int ACH = BM * 8;
    __shared__ bf16x8 As[2][ACH];
    __shared__ bf16x8 Bs[2][1024];
    const int nwg = gridDim.x;
    const int t0 = (blockIdx.x & 7) * (nwg >> 3) + (blockIdx.x >> 3);
    const int MT = M / BM;
    const int NBX = nwg / MT;
    const int srsize = NBX * 8;
    const int sr = t0 / srsize;
    const int rem = t0 - sr * srsize;
    const int bx = rem >> 3;
    const int by = sr * 8 + (rem & 7);
    const int bm = by * BM, bn = bx * 128;
    const int tid = threadIdx.x;
    const int l = tid & 63, w = tid >> 6;
    constexpr int MI = (BM == 128) ? 4 : 2;
    const int wr = (BM == 128) ? (w >> 1) * 64 : (w & 1) * 32;
    const int wc = (BM == 128) ? (w & 1) * 64 : (w >> 1) * 64;
    f32x4 acc[MI][4] = {};

    auto stage = [&](int k0, int sel) {
        #pragma unroll
        for (int p = 0; p < ACH / 256; ++p) {
            int u = p * 256 + tid;
            int row = u % BM, c = u / BM;
            const unsigned short* ga = A + (size_t)(bm + row) * K + k0 + c * 8;
            __builtin_amdgcn_global_load_lds(
                (const __attribute__((address_space(1))) unsigned int*)ga,
                (__attribute__((address_space(3))) unsigned int*)(&As[sel][u]), 16, 0, 0);
        }
        #pragma unroll
        for (int p = 0; p < 4; ++p) {
            int u = p * 256 + tid;
            int col = u & 127, c = u >> 7;
            const unsigned short* gb = B + (size_t)(bn + col) * K + k0 + c * 8;
            __builtin_amdgcn_global_load_lds(
                (const __attribute__((address_space(1))) unsigned int*)gb,
                (__attribute__((address_space(3))) unsigned int*)(&Bs[sel][u]), 16, 0, 0);
        }
    };
    auto compute = [&](int sel) {
        #pragma unroll
        for (int s = 0; s < 2; ++s) {
            const int cidx = s * 4 + (l >> 4);
            bf16x8 af[MI], bfr[4];
            #pragma unroll
            for (int mi = 0; mi < MI; ++mi) af[mi]  = As[sel][cidx * BM + wr + mi * 16 + (l & 15)];
            #pragma unroll
            for (int ni = 0; ni < 4; ++ni)  bfr[ni] = Bs[sel][cidx * 128 + wc + ni * 16 + (l & 15)];
            #pragma unroll
            for (int mi = 0; mi < MI; ++mi)
                #pragma unroll
                for (int ni = 0; ni < 4; ++ni)
                    acc[mi][ni] = __builtin_amdgcn_mfma_f32_16x16x32_bf16(
                        af[mi], bfr[ni], acc[mi][ni], 0, 0, 0);
        }
    };
    auto waitvm_spw = [&]() {
        if constexpr (BM == 128) asm volatile("s_waitcnt vmcnt(8)" ::: "memory");
        else                     asm volatile("s_waitcnt vmcnt(6)" ::: "memory");
    };
    auto waitvm0  = [&]() { asm volatile("s_waitcnt vmcnt(0)" ::: "memory"); };
    auto waitlgkm = [&]() { asm volatile("s_waitcnt lgkmcnt(0)" ::: "memory"); };
    auto bar      = [&]() { __builtin_amdgcn_s_barrier(); };

    const int NT = K >> 6;
    stage(0, 0);
    stage(64, 1);
    waitvm_spw();
    bar();
    for (int t = 0; t < NT; t += 2) {
        compute(0);
        waitlgkm(); bar();
        if (t + 2 < NT) { stage((t + 2) << 6, 0); waitvm_spw(); }
        else            { waitvm0(); }
        bar();
        compute(1);
        waitlgkm(); bar();
        if (t + 3 < NT) { stage((t + 3) << 6, 1); waitvm_spw(); }
        else            { waitvm0(); }
        bar();
    }

    #pragma unroll
    for (int mi = 0; mi < MI; ++mi) {
        #pragma unroll
        for (int r = 0; r < 4; ++r) {
            const int row = bm + wr + mi * 16 + (l >> 4) * 4 + r;
            #pragma unroll
            for (int ni = 0; ni < 4; ++ni) {
                const int col = bn + wc + ni * 16 + (l & 15);
                if (col < N) {
                    float v = acc[mi][ni][r];
                    if (bias) v += bias[col];
                    if (GELU) v = 0.5f * v * (1.0f + erff(v * 0.70710678118654752f));
                    if (RES)  v += res[(size_t)row * N + col];
                    if (OUTF == 0) ((float*)Cout)[(size_t)row * N + col] = v;
                    else ((unsigned short*)Cout)[(size_t)row * N + col] = f2bf(v);
                }
            }
        }
    }
}

// ---------------- bf16 MFMA causal flash attention ----------------
__global__ __launch_bounds__(256)
void attn_mfma(const unsigned short* __restrict__ qkv, unsigned short* __restrict__ ao) {
    const int qt = gridDim.x - 1 - blockIdx.x;
    const int h = blockIdx.y, b = blockIdx.z;
    const int tid = threadIdx.x;
    const int w = tid >> 6, l = tid & 63;
    const int c = l & 15, g = l >> 4;

    __shared__ unsigned short Ks[32 * 64];
    __shared__ unsigned short Vt[64 * 40];
    __shared__ unsigned int   Ps[4][16 * 20];

    const unsigned short* base = qkv + (size_t)(b * SEQ) * DQKV + h * HEAD;
    const int q0 = qt * 64 + w * 16;

    bf16x8 qf[2];
    {
        const unsigned short* qp = base + (size_t)(q0 + c) * DQKV + g * 8;
        qf[0] = *reinterpret_cast<const bf16x8*>(qp);
        qf[1] = *reinterpret_cast<const bf16x8*>(qp + 32);
    }

    f32x4 o_acc[4] = {};
    float m_run[4]  = {-INFINITY, -INFINITY, -INFINITY, -INFINITY};
    float l_run[4]  = {0.f, 0.f, 0.f, 0.f};

    const int srow = tid >> 3, schunk = tid & 7;
    const int vd = tid & 63, vw = tid >> 6;

    const int nkt = 2 * qt + 2;
    for (int kt = 0; kt < nkt; ++kt) {
        {
            const unsigned short* kp = base + (size_t)(kt * 32 + srow) * DQKV + 768 + schunk * 8;
            bf16x8 kv = *reinterpret_cast<const bf16x8*>(kp);
            *reinterpret_cast<bf16x8*>(&Ks[srow * 64 + ((schunk ^ (srow & 7)) * 8)]) = kv;
        }
        {
            unsigned short vv[8];
            #pragma unroll
            for (int j = 0; j < 8; ++j)
                vv[j] = base[(size_t)(kt * 32 + vw * 8 + j) * DQKV + 1536 + vd];
            uint4 pk;
            pk.x = vv[0] | ((unsigned)vv[1] << 16);
            pk.y = vv[2] | ((unsigned)vv[3] << 16);
            pk.z = vv[4] | ((unsigned)vv[5] << 16);
            pk.w = vv[6] | ((unsigned)vv[7] << 16);
            *reinterpret_cast<uint4*>(&Vt[vd * 40 + vw * 8]) = pk;
        }
        __syncthreads();

        f32x4 s_acc[2] = {};
        #pragma unroll
        for (int t = 0; t < 2; ++t) {
            const int kr = t * 16 + c;
            #pragma unroll
            for (int ks = 0; ks < 2; ++ks) {
                bf16x8 kf = *reinterpret_cast<const bf16x8*>(
                    &Ks[kr * 64 + (((ks * 4 + g) ^ (kr & 7)) * 8)]);
                s_acc[t] = __builtin_amdgcn_mfma_f32_16x16x32_bf16(qf[ks], kf, s_acc[t], 0, 0, 0);
            }
        }
        float sc[2][4];
        #pragma unroll
        for (int t = 0; t < 2; ++t) {
            const int kglob = kt * 32 + t * 16 + c;
            #pragma unroll
            for (int r = 0; r < 4; ++r) {
                float v = s_acc[t][r] * 0.125f;
                sc[t][r] = (kglob > q0 + g * 4 + r) ? -1e30f : v;
            }
        }
        float pout[2][4];
        #pragma unroll
        for (int r = 0; r < 4; ++r) {
            float tmax = fmaxf(sc[0][r], sc[1][r]);
            #pragma unroll
            for (int ms = 1; ms < 16; ms <<= 1) tmax = fmaxf(tmax, __shfl_xor(tmax, ms));
            float mnew = fmaxf(m_run[r], tmax);
            float alpha = __expf(m_run[r] - mnew);
            float p0 = __expf(sc[0][r] - mnew);
            float p1 = __expf(sc[1][r] - mnew);
            float psum = p0 + p1;
            #pragma unroll
            for (int ms = 1; ms < 16; ms <<= 1) psum += __shfl_xor(psum, ms);
            l_run[r] = l_run[r] * alpha + psum;
            m_run[r] = mnew;
            #pragma unroll
            for (int dt = 0; dt < 4; ++dt) o_acc[dt][r] *= alpha;
            pout[0][r] = p0; pout[1][r] = p1;
        }
        #pragma unroll
        for (int t = 0; t < 2; ++t) {
            #pragma unroll
            for (int r = 0; r < 4; ++r) {
                int my = f2bf(pout[t][r]);
                int part = __shfl_xor(my, 1);
                unsigned int word = (c & 1) ? ((unsigned)(part & 0xffff) | ((unsigned)my << 16))
                                            : ((unsigned)(my & 0xffff) | ((unsigned)part << 16));
                Ps[w][(g * 4 + r) * 20 + t * 8 + (c >> 1)] = word;
            }
        }
        uint4 praw = *reinterpret_cast<const uint4*>(&Ps[w][c * 20 + g * 4]);
        bf16x8 pf = *reinterpret_cast<const bf16x8*>(&praw);
        #pragma unroll
        for (int dt = 0; dt < 4; ++dt) {
            bf16x8 vf = *reinterpret_cast<const bf16x8*>(&Vt[(dt * 16 + c) * 40 + g * 8]);
            o_acc[dt] = __builtin_amdgcn_mfma_f32_16x16x32_bf16(pf, vf, o_acc[dt], 0, 0, 0);
        }
        __syncthreads();
    }

    float inv[4];
    #pragma unroll
    for (int r = 0; r < 4; ++r) inv[r] = 1.0f / l_run[r];
    #pragma unroll
    for (int r = 0; r < 4; ++r) {
        unsigned short* op = ao + (size_t)(b * SEQ + q0 + g * 4 + r) * D_MODEL + h * HEAD + c;
        #pragma unroll
        for (int dt = 0; dt < 4; ++dt)
            op[dt * 16] = f2bf(o_acc[dt][r] * inv[r]);
    }
}

extern "C" void kernel_launch(void* const* d_in, const int* in_sizes, int n_in,
                              void* d_out, int out_size, void* d_ws, size_t ws_size,
                              hipStream_t stream) {
    const int*   idx     = (const int*)  d_in[0];
    const float* tok_emb = (const float*)d_in[1];
    const float* pos_emb = (const float*)d_in[2];
    const float* Wq      = (const float*)d_in[3];
    const float* bq      = (const float*)d_in[4];
    const float* Wk      = (const float*)d_in[5];
    const float* bk      = (const float*)d_in[6];
    const float* Wv      = (const float*)d_in[7];
    const float* bv      = (const float*)d_in[8];
    const float* Wproj   = (const float*)d_in[9];
    const float* bproj   = (const float*)d_in[10];
    const float* ln1g    = (const float*)d_in[11];
    const float* ln1b    = (const float*)d_in[12];
    const float* ln2g    = (const float*)d_in[13];
    const float* ln2b    = (const float*)d_in[14];
    const float* Wf1     = (const float*)d_in[15];
    const float* bf1     = (const float*)d_in[16];
    const float* Wf2     = (const float*)d_in[17];
    const float* bf2     = (const float*)d_in[18];
    const float* lnfg    = (const float*)d_in[19];
    const float* lnfb    = (const float*)d_in[20];
    const float* Wlm     = (const float*)d_in[21];
    float* outp = (float*)d_out;

    char* basep = (char*)d_ws;
    size_t off = 0;
    auto alloc = [&](size_t bytes) -> void* {
        void* p = basep + off;
        off = (off + bytes + 255) & ~(size_t)255;
        return p;
    };
    float*          x      = (float*)         alloc((size_t)NROWS * D_MODEL * 4);
    unsigned short* qkv    = (unsigned short*)alloc((size_t)NROWS * DQKV * 2);
    unsigned short* hb     = (unsigned short*)alloc((size_t)NROWS * D_MODEL * 2);
    unsigned short* ao     = (unsigned short*)alloc((size_t)NROWS * D_MODEL * 2);
    unsigned short* mid    = (unsigned short*)alloc((size_t)NROWS * DFFN * 2);
    unsigned short* Wqkvb  = (unsigned short*)alloc((size_t)NLAYER * DQKV * D_MODEL * 2);
    unsigned short* Wprojb = (unsigned short*)alloc((size_t)NLAYER * D_MODEL * D_MODEL * 2);
    unsigned short* Wf1b   = (unsigned short*)alloc((size_t)NLAYER * DFFN * D_MODEL * 2);
    unsigned short* Wf2b   = (unsigned short*)alloc((size_t)NLAYER * D_MODEL * DFFN * 2);
    unsigned short* Wlmb   = (unsigned short*)alloc((size_t)VPAD * D_MODEL * 2);
    float*          bqkv   = (float*)         alloc((size_t)NLAYER * DQKV * 4);

    dim3 blk(256);
    dim3 tblk(32, 8);

    conv_lm<<<2048, blk, 0, stream>>>(Wlm, Wlmb);
    conv_transpose<1><<<dim3(24, 24, 6), tblk, 0, stream>>>(Wq, Wqkvb,             768, 768,  (size_t)768*768,  (size_t)DQKV*768);
    conv_transpose<1><<<dim3(24, 24, 6), tblk, 0, stream>>>(Wk, Wqkvb + 768*768,   768, 768,  (size_t)768*768,  (size_t)DQKV*768);
    conv_transpose<1><<<dim3(24, 24, 6), tblk, 0, stream>>>(Wv, Wqkvb + 2*768*768, 768, 768,  (size_t)768*768,  (size_t)DQKV*768);
    conv_transpose<0><<<dim3(24, 24, 6), tblk, 0, stream>>>(Wproj, Wprojb,         768, 768,  (size_t)768*768,  (size_t)768*768);
    conv_transpose<0><<<dim3(96, 24, 6), tblk, 0, stream>>>(Wf1, Wf1b,             768, 3072, (size_t)768*3072, (size_t)3072*768);
    conv_transpose<0><<<dim3(24, 96, 6), tblk, 0, stream>>>(Wf2, Wf2b,             3072, 768, (size_t)3072*768, (size_t)768*3072);
    conv_bias<<<(NLAYER * DQKV + 255) / 256, blk, 0, stream>>>(bq, bk, bv, bqkv);

    embed_kernel<<<NROWS, blk, 0, stream>>>(idx, tok_emb, pos_emb, x);

    dim3 gqkv(18 * 32);                  // BM=128
    dim3 g768s(6 * 64);                  // BM=64  (proj, FFN2)
    dim3 g3072(24 * 32);                 // BM=128
    dim3 ga(SEQ / 64, N_HEAD, BATCH);    // (16, 12, 4)

    for (int li = 0; li < NLAYER; ++li) {
        ln_kernel<<<NROWS, blk, 0, stream>>>(x, ln1g + li * D_MODEL, ln1b + li * D_MODEL, hb);

        gemm_mfma<128, 1, false, false><<<gqkv, blk, 0, stream>>>(
            hb, Wqkvb + (size_t)li * DQKV * D_MODEL, bqkv + li * DQKV, nullptr,
            qkv, NROWS, DQKV, D_MODEL);

        attn_mfma<<<ga, blk, 0, stream>>>(qkv, ao);

        gemm_mfma<64, 0, false, true><<<g768s, blk, 0, stream>>>(
            ao, Wprojb + (size_t)li * D_MODEL * D_MODEL, bproj + li * D_MODEL, x,
            x, NROWS, D_MODEL, D_MODEL);

        ln_kernel<<<NROWS, blk, 0, stream>>>(x, ln2g + li * D_MODEL, ln2b + li * D_MODEL, hb);

        gemm_mfma<128, 1, true, false><<<g3072, blk, 0, stream>>>(
            hb, Wf1b + (size_t)li * DFFN * D_MODEL, bf1 + li * DFFN, nullptr,
            mid, NROWS, DFFN, D_MODEL);

        gemm_mfma<64, 0, false, true><<<g768s, blk, 0, stream>>>(
            mid, Wf2b + (size_t)li * D_MODEL * DFFN, bf2 + li * D_MODEL, x,
            x, NROWS, D_MODEL, DFFN);
    }

    ln_kernel<<<NROWS, blk, 0, stream>>>(x, lnfg, lnfb, hb);

    dim3 gl((VPAD / 256) * (NROWS / 256));   // 197 * 16 = 3152 blocks
    gemm256_mfma<<<gl, dim3(512), 0, stream>>>(hb, Wlmb, outp, NROWS, VOCAB, D_MODEL);
}

// Round 8
// 2336.435 us; speedup vs baseline: 1.3611x; 1.1830x over previous
//
#include <hip/hip_runtime.h>
#include <hip/hip_bf16.h>
#include <math.h>

#define D_MODEL 768
#define N_HEAD  12
#define HEAD    64
#define SEQ     1024
#define NLAYER  6
#define BATCH   4
#define NROWS   (BATCH*SEQ)   // 4096
#define VOCAB   50257
#define VPAD    50432         // 197*256
#define DFFN    3072
#define DQKV    2304

typedef __attribute__((ext_vector_type(8))) __bf16 bf16x8;
typedef __attribute__((ext_vector_type(4))) float f32x4;
typedef __attribute__((ext_vector_type(4))) unsigned short u16x4;

__device__ inline unsigned short f2bf(float x) {
    __hip_bfloat16 h = __float2bfloat16(x);
    return *reinterpret_cast<unsigned short*>(&h);
}

// ---------------- embedding ----------------
__global__ __launch_bounds__(256)
void embed_kernel(const int* __restrict__ idx, const float* __restrict__ tok,
                  const float* __restrict__ pos, float* __restrict__ x) {
    int row = blockIdx.x;
    int t = idx[row];
    int s = row & (SEQ - 1);
    const float* tp = tok + (size_t)t * D_MODEL;
    const float* pp = pos + (size_t)s * D_MODEL;
    float* xp = x + (size_t)row * D_MODEL;
    for (int i = threadIdx.x; i < D_MODEL; i += 256) xp[i] = tp[i] + pp[i];
}

// ---------------- layernorm: fp32 in, bf16 out ----------------
__global__ __launch_bounds__(256)
void ln_kernel(const float* __restrict__ in, const float* __restrict__ gw,
               const float* __restrict__ bw, unsigned short* __restrict__ out) {
    int row = blockIdx.x;
    int tid = threadIdx.x;
    const float* x = in + (size_t)row * D_MODEL;
    float v0 = x[tid], v1 = x[tid + 256], v2 = x[tid + 512];
    float s  = v0 + v1 + v2;
    float sq = v0*v0 + v1*v1 + v2*v2;
    #pragma unroll
    for (int o = 1; o < 64; o <<= 1) { s += __shfl_xor(s, o); sq += __shfl_xor(sq, o); }
    __shared__ float red[8];
    int wave = tid >> 6;
    if ((tid & 63) == 0) { red[wave] = s; red[4 + wave] = sq; }
    __syncthreads();
    s  = red[0] + red[1] + red[2] + red[3];
    sq = red[4] + red[5] + red[6] + red[7];
    float mean = s * (1.0f / D_MODEL);
    float var  = sq * (1.0f / D_MODEL) - mean * mean;
    float rstd = rsqrtf(var + 1e-5f);
    unsigned short* op = out + (size_t)row * D_MODEL;
    op[tid]       = f2bf((v0 - mean) * rstd * gw[tid]       + bw[tid]);
    op[tid + 256] = f2bf((v1 - mean) * rstd * gw[tid + 256] + bw[tid + 256]);
    op[tid + 512] = f2bf((v2 - mean) * rstd * gw[tid + 512] + bw[tid + 512]);
}

// ---------------- weight conversion ----------------
template<int MODE>
__global__ __launch_bounds__(256)
void conv_transpose(const float* __restrict__ in, unsigned short* __restrict__ out,
                    int K, int N, size_t inLstride, size_t outLstride) {
    __shared__ float t[32][33];
    const int tx = threadIdx.x, ty = threadIdx.y;
    const int n0 = blockIdx.x * 32, k0 = blockIdx.y * 32;
    const float* ip = in + blockIdx.z * inLstride;
    unsigned short* op = out + blockIdx.z * outLstride;
    #pragma unroll
    for (int j = 0; j < 4; ++j) {
        int k = k0 + ty + j * 8, n = n0 + tx;
        float v = (MODE == 0) ? ip[(size_t)k * N + n]
                              : ip[(size_t)((n >> 6) * K + k) * 64 + (n & 63)];
        t[ty + j * 8][tx] = v;
    }
    __syncthreads();
    #pragma unroll
    for (int j = 0; j < 4; ++j) {
        int n = n0 + ty + j * 8, k = k0 + tx;
        op[(size_t)n * K + k] = f2bf(t[tx][ty + j * 8]);
    }
}

__global__ __launch_bounds__(256)
void conv_lm(const float* __restrict__ in, unsigned short* __restrict__ out) {
    const int nchunks = VPAD * D_MODEL / 4;
    const int vchunks = VOCAB * D_MODEL / 4;
    for (int i = blockIdx.x * 256 + threadIdx.x; i < nchunks; i += gridDim.x * 256) {
        u16x4 o;
        if (i < vchunks) {
            float4 v = reinterpret_cast<const float4*>(in)[i];
            o[0] = f2bf(v.x); o[1] = f2bf(v.y); o[2] = f2bf(v.z); o[3] = f2bf(v.w);
        } else { o[0] = 0; o[1] = 0; o[2] = 0; o[3] = 0; }
        reinterpret_cast<u16x4*>(out)[i] = o;
    }
}

__global__ __launch_bounds__(256)
void conv_bias(const float* __restrict__ bq, const float* __restrict__ bk,
               const float* __restrict__ bv, float* __restrict__ out) {
    int i = blockIdx.x * 256 + threadIdx.x;
    if (i >= NLAYER * DQKV) return;
    int l = i / DQKV, n = i % DQKV;
    float v;
    if (n < 768)        v = bq[l * 768 + n];
    else if (n < 1536)  v = bk[l * 768 + n - 768];
    else                v = bv[l * 768 + n - 1536];
    out[i] = v;
}

// ---------------- 256x256 bf16 MFMA GEMM (logits) ----------------
// Proven round-6 schedule: issue-early full-tile staging, one vmcnt(0)+barrier
// per K-tile, XOR-swizzled LDS both-sides, setprio MFMA clusters.
__global__ __launch_bounds__(512)
void gemm256_mfma(const unsigned short* __restrict__ A, const unsigned short* __restrict__ B,
                  float* __restrict__ C, int M, int N, int K) {
    __shared__ unsigned short smem[2 * 2 * 16384];   // 128 KiB
    const int nwg = gridDim.x;
    const int t0 = (blockIdx.x & 7) * (nwg >> 3) + (blockIdx.x >> 3);
    const int MT = M >> 8;
    const int NBX = nwg / MT;
    const int srsize = NBX * 8;
    const int sr = t0 / srsize;
    const int rem = t0 - sr * srsize;
    const int bx = rem >> 3;
    const int by = sr * 8 + (rem & 7);
    const int bm = by * 256, bn = bx * 256;
    const int tid = threadIdx.x;
    const int l = tid & 63, w = tid >> 6;
    const int wm = w >> 2, wn = w & 3;
    const int lr = l & 15, lc = l >> 4;
    f32x4 acc[8][4] = {};

    auto stage = [&](int k0, int buf) {
        #pragma unroll
        for (int p = 0; p < 4; ++p) {
            int d16 = p * 512 + tid;
            int row = d16 >> 3, cph = d16 & 7;
            int clog = cph ^ (row & 7);
            const unsigned short* ga = A + (size_t)(bm + row) * K + k0 + clog * 8;
            __builtin_amdgcn_global_load_lds(
                (const __attribute__((address_space(1))) unsigned int*)ga,
                (__attribute__((address_space(3))) unsigned int*)(&smem[buf * 32768 + d16 * 8]), 16, 0, 0);
        }
        #pragma unroll
        for (int p = 0; p < 4; ++p) {
            int d16 = p * 512 + tid;
            int row = d16 >> 3, cph = d16 & 7;
            int clog = cph ^ (row & 7);
            const unsigned short* gb = B + (size_t)(bn + row) * K + k0 + clog * 8;
            __builtin_amdgcn_global_load_lds(
                (const __attribute__((address_space(1))) unsigned int*)gb,
                (__attribute__((address_space(3))) unsigned int*)(&smem[buf * 32768 + 16384 + d16 * 8]), 16, 0, 0);
        }
    };

    auto compute = [&](int buf) {
        const unsigned short* Ab = &smem[buf * 32768];
        const unsigned short* Bb = &smem[buf * 32768 + 16384];
        #pragma unroll
        for (int qm = 0; qm < 2; ++qm) {
            bf16x8 af[2][4];
            #pragma unroll
            for (int ks = 0; ks < 2; ++ks)
                #pragma unroll
                for (int mi = 0; mi < 4; ++mi) {
                    int row = wm * 128 + qm * 64 + mi * 16 + lr;
                    af[ks][mi] = *reinterpret_cast<const bf16x8*>(
                        &Ab[row * 64 + (((ks * 4 + lc) ^ (row & 7)) * 8)]);
                }
            #pragma unroll
            for (int qn = 0; qn < 2; ++qn) {
                bf16x8 bfr[2][2];
                #pragma unroll
                for (int ks = 0; ks < 2; ++ks)
                    #pragma unroll
                    for (int ni = 0; ni < 2; ++ni) {
                        int col = wn * 64 + qn * 32 + ni * 16 + lr;
                        bfr[ks][ni] = *reinterpret_cast<const bf16x8*>(
                            &Bb[col * 64 + (((ks * 4 + lc) ^ (col & 7)) * 8)]);
                    }
                __builtin_amdgcn_s_setprio(1);
                #pragma unroll
                for (int ks = 0; ks < 2; ++ks)
                    #pragma unroll
                    for (int mi = 0; mi < 4; ++mi)
                        #pragma unroll
                        for (int ni = 0; ni < 2; ++ni)
                            acc[qm * 4 + mi][qn * 2 + ni] = __builtin_amdgcn_mfma_f32_16x16x32_bf16(
                                af[ks][mi], bfr[ks][ni], acc[qm * 4 + mi][qn * 2 + ni], 0, 0, 0);
                __builtin_amdgcn_s_setprio(0);
            }
        }
    };

    const int NT = K >> 6;
    stage(0, 0);
    asm volatile("s_waitcnt vmcnt(0)" ::: "memory");
    __builtin_amdgcn_s_barrier();
    for (int t = 0; t < NT; ++t) {
        const int cur = t & 1;
        if (t + 1 < NT) stage((t + 1) << 6, cur ^ 1);
        compute(cur);
        if (t + 1 < NT) {
            asm volatile("s_waitcnt vmcnt(0)" ::: "memory");
            __builtin_amdgcn_s_barrier();
        }
    }

    #pragma unroll
    for (int i = 0; i < 8; ++i) {
        #pragma unroll
        for (int r = 0; r < 4; ++r) {
            const int row = bm + wm * 128 + i * 16 + lc * 4 + r;
            #pragma unroll
            for (int j = 0; j < 4; ++j) {
                const int col = bn + wn * 64 + j * 16 + lr;
                if (col < N) C[(size_t)row * N + col] = acc[i][j][r];
            }
        }
    }
}

// ---------------- 128x128 bf16 MFMA GEMM (layer GEMMs) ----------------
// Same proven schedule as gemm256, 4 waves (2x2), 64KB LDS -> 2 blocks/CU.
// C[M,N] = A[M,K] @ B[N,K]^T + bias (+GELU) (+res). N%128==0, K%64==0.
template<int OUTF /*0=f32,1=bf16*/, bool GELU, bool RES>
__global__ __launch_bounds__(256)
void gemm128p(const unsigned short* __restrict__ A, const unsigned short* __restrict__ B,
              const float* __restrict__ bias, const float* __restrict__ res,
              void* __restrict__ Cout, int M, int N, int K) {
    __shared__ unsigned short smem[2 * 2 * 8192];    // 64 KiB
    const int nwg = gridDim.x;
    const int t0 = (blockIdx.x & 7) * (nwg >> 3) + (blockIdx.x >> 3);
    const int MT = M >> 7;
    const int NBX = nwg / MT;
    const int srsize = NBX * 8;
    const int sr = t0 / srsize;
    const int rem = t0 - sr * srsize;
    const int bx = rem >> 3;
    const int by = sr * 8 + (rem & 7);
    const int bm = by * 128, bn = bx * 128;
    const int tid = threadIdx.x;
    const int l = tid & 63, w = tid >> 6;
    const int wr = (w >> 1) * 64, wc = (w & 1) * 64;
    const int lr = l & 15, lc = l >> 4;
    f32x4 acc[4][4] = {};

    auto stage = [&](int k0, int buf) {
        #pragma unroll
        for (int p = 0; p < 4; ++p) {
            int d16 = p * 256 + tid;          // 1024 chunks: 128 rows x 8
            int row = d16 >> 3, cph = d16 & 7;
            int clog = cph ^ (row & 7);
            const unsigned short* ga = A + (size_t)(bm + row) * K + k0 + clog * 8;
            __builtin_amdgcn_global_load_lds(
                (const __attribute__((address_space(1))) unsigned int*)ga,
                (__attribute__((address_space(3))) unsigned int*)(&smem[buf * 16384 + d16 * 8]), 16, 0, 0);
        }
        #pragma unroll
        for (int p = 0; p < 4; ++p) {
            int d16 = p * 256 + tid;
            int row = d16 >> 3, cph = d16 & 7;
            int clog = cph ^ (row & 7);
            const unsigned short* gb = B + (size_t)(bn + row) * K + k0 + clog * 8;
            __builtin_amdgcn_global_load_lds(
                (const __attribute__((address_space(1))) unsigned int*)gb,
                (__attribute__((address_space(3))) unsigned int*)(&smem[buf * 16384 + 8192 + d16 * 8]), 16, 0, 0);
        }
    };

    auto compute = [&](int buf) {
        const unsigned short* Ab = &smem[buf * 16384];
        const unsigned short* Bb = &smem[buf * 16384 + 8192];
        #pragma unroll
        for (int ks = 0; ks < 2; ++ks) {
            bf16x8 af[4], bfr[4];
            #pragma unroll
            for (int mi = 0; mi < 4; ++mi) {
                int row = wr + mi * 16 + lr;
                af[mi] = *reinterpret_cast<const bf16x8*>(
                    &Ab[row * 64 + (((ks * 4 + lc) ^ (row & 7)) * 8)]);
            }
            #pragma unroll
            for (int ni = 0; ni < 4; ++ni) {
                int col = wc + ni * 16 + lr;
                bfr[ni] = *reinterpret_cast<const bf16x8*>(
                    &Bb[col * 64 + (((ks * 4 + lc) ^ (col & 7)) * 8)]);
            }
            __builtin_amdgcn_s_setprio(1);
            #pragma unroll
            for (int mi = 0; mi < 4; ++mi)
                #pragma unroll
                for (int ni = 0; ni < 4; ++ni)
                    acc[mi][ni] = __builtin_amdgcn_mfma_f32_16x16x32_bf16(
                        af[mi], bfr[ni], acc[mi][ni], 0, 0, 0);
            __builtin_amdgcn_s_setprio(0);
        }
    };

    const int NT = K >> 6;
    stage(0, 0);
    asm volatile("s_waitcnt vmcnt(0)" ::: "memory");
    __builtin_amdgcn_s_barrier();
    for (int t = 0; t < NT; ++t) {
        const int cur = t & 1;
        if (t + 1 < NT) stage((t + 1) << 6, cur ^ 1);
        compute(cur);
        if (t + 1 < NT) {
            asm volatile("s_waitcnt vmcnt(0)" ::: "memory");
            __builtin_amdgcn_s_barrier();
        }
    }

    #pragma unroll
    for (int mi = 0; mi < 4; ++mi) {
        #pragma unroll
        for (int r = 0; r < 4; ++r) {
            const int row = bm + wr + mi * 16 + lc * 4 + r;
            #pragma unroll
            for (int ni = 0; ni < 4; ++ni) {
                const int col = bn + wc + ni * 16 + lr;
                float v = acc[mi][ni][r];
                if (bias) v += bias[col];
                if (GELU) v = 0.5f * v * (1.0f + erff(v * 0.70710678118654752f));
                if (RES)  v += res[(size_t)row * N + col];
                if (OUTF == 0) ((float*)Cout)[(size_t)row * N + col] = v;
                else ((unsigned short*)Cout)[(size_t)row * N + col] = f2bf(v);
            }
        }
    }
}

// ---------------- bf16 MFMA causal flash attention ----------------
__global__ __launch_bounds__(256)
void attn_mfma(const unsigned short* __restrict__ qkv, unsigned short* __restrict__ ao) {
    const int qt = gridDim.x - 1 - blockIdx.x;
    const int h = blockIdx.y, b = blockIdx.z;
    const int tid = threadIdx.x;
    const int w = tid >> 6, l = tid & 63;
    const int c = l & 15, g = l >> 4;

    __shared__ unsigned short Ks[32 * 64];
    __shared__ unsigned short Vt[64 * 40];
    __shared__ unsigned int   Ps[4][16 * 20];

    const unsigned short* base = qkv + (size_t)(b * SEQ) * DQKV + h * HEAD;
    const int q0 = qt * 64 + w * 16;

    bf16x8 qf[2];
    {
        const unsigned short* qp = base + (size_t)(q0 + c) * DQKV + g * 8;
        qf[0] = *reinterpret_cast<const bf16x8*>(qp);
        qf[1] = *reinterpret_cast<const bf16x8*>(qp + 32);
    }

    f32x4 o_acc[4] = {};
    float m_run[4]  = {-INFINITY, -INFINITY, -INFINITY, -INFINITY};
    float l_run[4]  = {0.f, 0.f, 0.f, 0.f};

    const int srow = tid >> 3, schunk = tid & 7;
    const int vd = tid & 63, vw = tid >> 6;

    const int nkt = 2 * qt + 2;
    for (int kt = 0; kt < nkt; ++kt) {
        {
            const unsigned short* kp = base + (size_t)(kt * 32 + srow) * DQKV + 768 + schunk * 8;
            bf16x8 kv = *reinterpret_cast<const bf16x8*>(kp);
            *reinterpret_cast<bf16x8*>(&Ks[srow * 64 + ((schunk ^ (srow & 7)) * 8)]) = kv;
        }
        {
            unsigned short vv[8];
            #pragma unroll
            for (int j = 0; j < 8; ++j)
                vv[j] = base[(size_t)(kt * 32 + vw * 8 + j) * DQKV + 1536 + vd];
            uint4 pk;
            pk.x = vv[0] | ((unsigned)vv[1] << 16);
            pk.y = vv[2] | ((unsigned)vv[3] << 16);
            pk.z = vv[4] | ((unsigned)vv[5] << 16);
            pk.w = vv[6] | ((unsigned)vv[7] << 16);
            *reinterpret_cast<uint4*>(&Vt[vd * 40 + vw * 8]) = pk;
        }
        __syncthreads();

        f32x4 s_acc[2] = {};
        #pragma unroll
        for (int t = 0; t < 2; ++t) {
            const int kr = t * 16 + c;
            #pragma unroll
            for (int ks = 0; ks < 2; ++ks) {
                bf16x8 kf = *reinterpret_cast<const bf16x8*>(
                    &Ks[kr * 64 + (((ks * 4 + g) ^ (kr & 7)) * 8)]);
                s_acc[t] = __builtin_amdgcn_mfma_f32_16x16x32_bf16(qf[ks], kf, s_acc[t], 0, 0, 0);
            }
        }
        float sc[2][4];
        #pragma unroll
        for (int t = 0; t < 2; ++t) {
            const int kglob = kt * 32 + t * 16 + c;
            #pragma unroll
            for (int r = 0; r < 4; ++r) {
                float v = s_acc[t][r] * 0.125f;
                sc[t][r] = (kglob > q0 + g * 4 + r) ? -1e30f : v;
            }
        }
        float pout[2][4];
        #pragma unroll
        for (int r = 0; r < 4; ++r) {
            float tmax = fmaxf(sc[0][r], sc[1][r]);
            #pragma unroll
            for (int ms = 1; ms < 16; ms <<= 1) tmax = fmaxf(tmax, __shfl_xor(tmax, ms));
            float mnew = fmaxf(m_run[r], tmax);
            float alpha = __expf(m_run[r] - mnew);
            float p0 = __expf(sc[0][r] - mnew);
            float p1 = __expf(sc[1][r] - mnew);
            float psum = p0 + p1;
            #pragma unroll
            for (int ms = 1; ms < 16; ms <<= 1) psum += __shfl_xor(psum, ms);
            l_run[r] = l_run[r] * alpha + psum;
            m_run[r] = mnew;
            #pragma unroll
            for (int dt = 0; dt < 4; ++dt) o_acc[dt][r] *= alpha;
            pout[0][r] = p0; pout[1][r] = p1;
        }
        #pragma unroll
        for (int t = 0; t < 2; ++t) {
            #pragma unroll
            for (int r = 0; r < 4; ++r) {
                int my = f2bf(pout[t][r]);
                int part = __shfl_xor(my, 1);
                unsigned int word = (c & 1) ? ((unsigned)(part & 0xffff) | ((unsigned)my << 16))
                                            : ((unsigned)(my & 0xffff) | ((unsigned)part << 16));
                Ps[w][(g * 4 + r) * 20 + t * 8 + (c >> 1)] = word;
            }
        }
        uint4 praw = *reinterpret_cast<const uint4*>(&Ps[w][c * 20 + g * 4]);
        bf16x8 pf = *reinterpret_cast<const bf16x8*>(&praw);
        #pragma unroll
        for (int dt = 0; dt < 4; ++dt) {
            bf16x8 vf = *reinterpret_cast<const bf16x8*>(&Vt[(dt * 16 + c) * 40 + g * 8]);
            o_acc[dt] = __builtin_amdgcn_mfma_f32_16x16x32_bf16(pf, vf, o_acc[dt], 0, 0, 0);
        }
        __syncthreads();
    }

    float inv[4];
    #pragma unroll
    for (int r = 0; r < 4; ++r) inv[r] = 1.0f / l_run[r];
    #pragma unroll
    for (int r = 0; r < 4; ++r) {
        unsigned short* op = ao + (size_t)(b * SEQ + q0 + g * 4 + r) * D_MODEL + h * HEAD + c;
        #pragma unroll
        for (int dt = 0; dt < 4; ++dt)
            op[dt * 16] = f2bf(o_acc[dt][r] * inv[r]);
    }
}

extern "C" void kernel_launch(void* const* d_in, const int* in_sizes, int n_in,
                              void* d_out, int out_size, void* d_ws, size_t ws_size,
                              hipStream_t stream) {
    const int*   idx     = (const int*)  d_in[0];
    const float* tok_emb = (const float*)d_in[1];
    const float* pos_emb = (const float*)d_in[2];
    const float* Wq      = (const float*)d_in[3];
    const float* bq      = (const float*)d_in[4];
    const float* Wk      = (const float*)d_in[5];
    const float* bk      = (const float*)d_in[6];
    const float* Wv      = (const float*)d_in[7];
    const float* bv      = (const float*)d_in[8];
    const float* Wproj   = (const float*)d_in[9];
    const float* bproj   = (const float*)d_in[10];
    const float* ln1g    = (const float*)d_in[11];
    const float* ln1b    = (const float*)d_in[12];
    const float* ln2g    = (const float*)d_in[13];
    const float* ln2b    = (const float*)d_in[14];
    const float* Wf1     = (const float*)d_in[15];
    const float* bf1     = (const float*)d_in[16];
    const float* Wf2     = (const float*)d_in[17];
    const float* bf2     = (const float*)d_in[18];
    const float* lnfg    = (const float*)d_in[19];
    const float* lnfb    = (const float*)d_in[20];
    const float* Wlm     = (const float*)d_in[21];
    float* outp = (float*)d_out;

    char* basep = (char*)d_ws;
    size_t off = 0;
    auto alloc = [&](size_t bytes) -> void* {
        void* p = basep + off;
        off = (off + bytes + 255) & ~(size_t)255;
        return p;
    };
    float*          x      = (float*)         alloc((size_t)NROWS * D_MODEL * 4);
    unsigned short* qkv    = (unsigned short*)alloc((size_t)NROWS * DQKV * 2);
    unsigned short* hb     = (unsigned short*)alloc((size_t)NROWS * D_MODEL * 2);
    unsigned short* ao     = (unsigned short*)alloc((size_t)NROWS * D_MODEL * 2);
    unsigned short* mid    = (unsigned short*)alloc((size_t)NROWS * DFFN * 2);
    unsigned short* Wqkvb  = (unsigned short*)alloc((size_t)NLAYER * DQKV * D_MODEL * 2);
    unsigned short* Wprojb = (unsigned short*)alloc((size_t)NLAYER * D_MODEL * D_MODEL * 2);
    unsigned short* Wf1b   = (unsigned short*)alloc((size_t)NLAYER * DFFN * D_MODEL * 2);
    unsigned short* Wf2b   = (unsigned short*)alloc((size_t)NLAYER * D_MODEL * DFFN * 2);
    unsigned short* Wlmb   = (unsigned short*)alloc((size_t)VPAD * D_MODEL * 2);
    float*          bqkv   = (float*)         alloc((size_t)NLAYER * DQKV * 4);

    dim3 blk(256);
    dim3 tblk(32, 8);

    conv_lm<<<2048, blk, 0, stream>>>(Wlm, Wlmb);
    conv_transpose<1><<<dim3(24, 24, 6), tblk, 0, stream>>>(Wq, Wqkvb,             768, 768,  (size_t)768*768,  (size_t)DQKV*768);
    conv_transpose<1><<<dim3(24, 24, 6), tblk, 0, stream>>>(Wk, Wqkvb + 768*768,   768, 768,  (size_t)768*768,  (size_t)DQKV*768);
    conv_transpose<1><<<dim3(24, 24, 6), tblk, 0, stream>>>(Wv, Wqkvb + 2*768*768, 768, 768,  (size_t)768*768,  (size_t)DQKV*768);
    conv_transpose<0><<<dim3(24, 24, 6), tblk, 0, stream>>>(Wproj, Wprojb,         768, 768,  (size_t)768*768,  (size_t)768*768);
    conv_transpose<0><<<dim3(96, 24, 6), tblk, 0, stream>>>(Wf1, Wf1b,             768, 3072, (size_t)768*3072, (size_t)3072*768);
    conv_transpose<0><<<dim3(24, 96, 6), tblk, 0, stream>>>(Wf2, Wf2b,             3072, 768, (size_t)3072*768, (size_t)768*3072);
    conv_bias<<<(NLAYER * DQKV + 255) / 256, blk, 0, stream>>>(bq, bk, bv, bqkv);

    embed_kernel<<<NROWS, blk, 0, stream>>>(idx, tok_emb, pos_emb, x);

    dim3 gqkv(32 * 18);                  // 576 blocks
    dim3 g768(32 * 6);                   // 192 blocks (proj, FFN2)
    dim3 g3072(32 * 24);                 // 768 blocks (FFN1)
    dim3 ga(SEQ / 64, N_HEAD, BATCH);    // (16, 12, 4)

    for (int li = 0; li < NLAYER; ++li) {
        ln_kernel<<<NROWS, blk, 0, stream>>>(x, ln1g + li * D_MODEL, ln1b + li * D_MODEL, hb);

        gemm128p<1, false, false><<<gqkv, blk, 0, stream>>>(
            hb, Wqkvb + (size_t)li * DQKV * D_MODEL, bqkv + li * DQKV, nullptr,
            qkv, NROWS, DQKV, D_MODEL);

        attn_mfma<<<ga, blk, 0, stream>>>(qkv, ao);

        gemm128p<0, false, true><<<g768, blk, 0, stream>>>(
            ao, Wprojb + (size_t)li * D_MODEL * D_MODEL, bproj + li * D_MODEL, x,
            x, NROWS, D_MODEL, D_MODEL);

        ln_kernel<<<NROWS, blk, 0, stream>>>(x, ln2g + li * D_MODEL, ln2b + li * D_MODEL, hb);

        gemm128p<1, true, false><<<g3072, blk, 0, stream>>>(
            hb, Wf1b + (size_t)li * DFFN * D_MODEL, bf1 + li * DFFN, nullptr,
            mid, NROWS, DFFN, D_MODEL);

        gemm128p<0, false, true><<<g768, blk, 0, stream>>>(
            mid, Wf2b + (size_t)li * D_MODEL * DFFN, bf2 + li * D_MODEL, x,
            x, NROWS, D_MODEL, DFFN);
    }

    ln_kernel<<<NROWS, blk, 0, stream>>>(x, lnfg, lnfb, hb);

    dim3 gl((VPAD / 256) * (NROWS / 256));   // 197 * 16 = 3152 blocks
    gemm256_mfma<<<gl, dim3(512), 0, stream>>>(hb, Wlmb, outp, NROWS, VOCAB, D_MODEL);
}

// Round 9
// 2266.863 us; speedup vs baseline: 1.4029x; 1.0307x over previous
//
#include <hip/hip_runtime.h>
#include <hip/hip_bf16.h>
#include <math.h>

#define D_MODEL 768
#define N_HEAD  12
#define HEAD    64
#define SEQ     1024
#define NLAYER  6
#define BATCH   4
#define NROWS   (BATCH*SEQ)   // 4096
#define VOCAB   50257
#define VPAD    50432         // 197*256
#define DFFN    3072
#define DQKV    2304

typedef __attribute__((ext_vector_type(8))) __bf16 bf16x8;
typedef __attribute__((ext_vector_type(4))) float f32x4;
typedef __attribute__((ext_vector_type(4))) unsigned short u16x4;

__device__ inline unsigned short f2bf(float x) {
    __hip_bfloat16 h = __float2bfloat16(x);
    return *reinterpret_cast<unsigned short*>(&h);
}

// ---------------- embedding ----------------
__global__ __launch_bounds__(256)
void embed_kernel(const int* __restrict__ idx, const float* __restrict__ tok,
                  const float* __restrict__ pos, float* __restrict__ x) {
    int row = blockIdx.x;
    int t = idx[row];
    int s = row & (SEQ - 1);
    const float* tp = tok + (size_t)t * D_MODEL;
    const float* pp = pos + (size_t)s * D_MODEL;
    float* xp = x + (size_t)row * D_MODEL;
    for (int i = threadIdx.x; i < D_MODEL; i += 256) xp[i] = tp[i] + pp[i];
}

// ---------------- layernorm: fp32 in, bf16 out ----------------
__global__ __launch_bounds__(256)
void ln_kernel(const float* __restrict__ in, const float* __restrict__ gw,
               const float* __restrict__ bw, unsigned short* __restrict__ out) {
    int row = blockIdx.x;
    int tid = threadIdx.x;
    const float* x = in + (size_t)row * D_MODEL;
    float v0 = x[tid], v1 = x[tid + 256], v2 = x[tid + 512];
    float s  = v0 + v1 + v2;
    float sq = v0*v0 + v1*v1 + v2*v2;
    #pragma unroll
    for (int o = 1; o < 64; o <<= 1) { s += __shfl_xor(s, o); sq += __shfl_xor(sq, o); }
    __shared__ float red[8];
    int wave = tid >> 6;
    if ((tid & 63) == 0) { red[wave] = s; red[4 + wave] = sq; }
    __syncthreads();
    s  = red[0] + red[1] + red[2] + red[3];
    sq = red[4] + red[5] + red[6] + red[7];
    float mean = s * (1.0f / D_MODEL);
    float var  = sq * (1.0f / D_MODEL) - mean * mean;
    float rstd = rsqrtf(var + 1e-5f);
    unsigned short* op = out + (size_t)row * D_MODEL;
    op[tid]       = f2bf((v0 - mean) * rstd * gw[tid]       + bw[tid]);
    op[tid + 256] = f2bf((v1 - mean) * rstd * gw[tid + 256] + bw[tid + 256]);
    op[tid + 512] = f2bf((v2 - mean) * rstd * gw[tid + 512] + bw[tid + 512]);
}

// ---------------- weight conversion ----------------
template<int MODE>
__global__ __launch_bounds__(256)
void conv_transpose(const float* __restrict__ in, unsigned short* __restrict__ out,
                    int K, int N, size_t inLstride, size_t outLstride) {
    __shared__ float t[32][33];
    const int tx = threadIdx.x, ty = threadIdx.y;
    const int n0 = blockIdx.x * 32, k0 = blockIdx.y * 32;
    const float* ip = in + blockIdx.z * inLstride;
    unsigned short* op = out + blockIdx.z * outLstride;
    #pragma unroll
    for (int j = 0; j < 4; ++j) {
        int k = k0 + ty + j * 8, n = n0 + tx;
        float v = (MODE == 0) ? ip[(size_t)k * N + n]
                              : ip[(size_t)((n >> 6) * K + k) * 64 + (n & 63)];
        t[ty + j * 8][tx] = v;
    }
    __syncthreads();
    #pragma unroll
    for (int j = 0; j < 4; ++j) {
        int n = n0 + ty + j * 8, k = k0 + tx;
        op[(size_t)n * K + k] = f2bf(t[tx][ty + j * 8]);
    }
}

__global__ __launch_bounds__(256)
void conv_lm(const float* __restrict__ in, unsigned short* __restrict__ out) {
    const int nchunks = VPAD * D_MODEL / 4;
    const int vchunks = VOCAB * D_MODEL / 4;
    for (int i = blockIdx.x * 256 + threadIdx.x; i < nchunks; i += gridDim.x * 256) {
        u16x4 o;
        if (i < vchunks) {
            float4 v = reinterpret_cast<const float4*>(in)[i];
            o[0] = f2bf(v.x); o[1] = f2bf(v.y); o[2] = f2bf(v.z); o[3] = f2bf(v.w);
        } else { o[0] = 0; o[1] = 0; o[2] = 0; o[3] = 0; }
        reinterpret_cast<u16x4*>(out)[i] = o;
    }
}

__global__ __launch_bounds__(256)
void conv_bias(const float* __restrict__ bq, const float* __restrict__ bk,
               const float* __restrict__ bv, float* __restrict__ out) {
    int i = blockIdx.x * 256 + threadIdx.x;
    if (i >= NLAYER * DQKV) return;
    int l = i / DQKV, n = i % DQKV;
    float v;
    if (n < 768)        v = bq[l * 768 + n];
    else if (n < 1536)  v = bk[l * 768 + n - 768];
    else                v = bv[l * 768 + n - 1536];
    out[i] = v;
}

// ---------------- 256x256 bf16 MFMA GEMM (logits) ----------------
__global__ __launch_bounds__(512)
void gemm256_mfma(const unsigned short* __restrict__ A, const unsigned short* __restrict__ B,
                  float* __restrict__ C, int M, int N, int K) {
    __shared__ unsigned short smem[2 * 2 * 16384];   // 128 KiB
    const int nwg = gridDim.x;
    const int t0 = (blockIdx.x & 7) * (nwg >> 3) + (blockIdx.x >> 3);
    const int MT = M >> 8;
    const int NBX = nwg / MT;
    const int srsize = NBX * 8;
    const int sr = t0 / srsize;
    const int rem = t0 - sr * srsize;
    const int bx = rem >> 3;
    const int by = sr * 8 + (rem & 7);
    const int bm = by * 256, bn = bx * 256;
    const int tid = threadIdx.x;
    const int l = tid & 63, w = tid >> 6;
    const int wm = w >> 2, wn = w & 3;
    const int lr = l & 15, lc = l >> 4;
    f32x4 acc[8][4] = {};

    auto stage = [&](int k0, int buf) {
        #pragma unroll
        for (int p = 0; p < 4; ++p) {
            int d16 = p * 512 + tid;
            int row = d16 >> 3, cph = d16 & 7;
            int clog = cph ^ (row & 7);
            const unsigned short* ga = A + (size_t)(bm + row) * K + k0 + clog * 8;
            __builtin_amdgcn_global_load_lds(
                (const __attribute__((address_space(1))) unsigned int*)ga,
                (__attribute__((address_space(3))) unsigned int*)(&smem[buf * 32768 + d16 * 8]), 16, 0, 0);
        }
        #pragma unroll
        for (int p = 0; p < 4; ++p) {
            int d16 = p * 512 + tid;
            int row = d16 >> 3, cph = d16 & 7;
            int clog = cph ^ (row & 7);
            const unsigned short* gb = B + (size_t)(bn + row) * K + k0 + clog * 8;
            __builtin_amdgcn_global_load_lds(
                (const __attribute__((address_space(1))) unsigned int*)gb,
                (__attribute__((address_space(3))) unsigned int*)(&smem[buf * 32768 + 16384 + d16 * 8]), 16, 0, 0);
        }
    };

    auto compute = [&](int buf) {
        const unsigned short* Ab = &smem[buf * 32768];
        const unsigned short* Bb = &smem[buf * 32768 + 16384];
        #pragma unroll
        for (int qm = 0; qm < 2; ++qm) {
            bf16x8 af[2][4];
            #pragma unroll
            for (int ks = 0; ks < 2; ++ks)
                #pragma unroll
                for (int mi = 0; mi < 4; ++mi) {
                    int row = wm * 128 + qm * 64 + mi * 16 + lr;
                    af[ks][mi] = *reinterpret_cast<const bf16x8*>(
                        &Ab[row * 64 + (((ks * 4 + lc) ^ (row & 7)) * 8)]);
                }
            #pragma unroll
            for (int qn = 0; qn < 2; ++qn) {
                bf16x8 bfr[2][2];
                #pragma unroll
                for (int ks = 0; ks < 2; ++ks)
                    #pragma unroll
                    for (int ni = 0; ni < 2; ++ni) {
                        int col = wn * 64 + qn * 32 + ni * 16 + lr;
                        bfr[ks][ni] = *reinterpret_cast<const bf16x8*>(
                            &Bb[col * 64 + (((ks * 4 + lc) ^ (col & 7)) * 8)]);
                    }
                __builtin_amdgcn_s_setprio(1);
                #pragma unroll
                for (int ks = 0; ks < 2; ++ks)
                    #pragma unroll
                    for (int mi = 0; mi < 4; ++mi)
                        #pragma unroll
                        for (int ni = 0; ni < 2; ++ni)
                            acc[qm * 4 + mi][qn * 2 + ni] = __builtin_amdgcn_mfma_f32_16x16x32_bf16(
                                af[ks][mi], bfr[ks][ni], acc[qm * 4 + mi][qn * 2 + ni], 0, 0, 0);
                __builtin_amdgcn_s_setprio(0);
            }
        }
    };

    const int NT = K >> 6;
    stage(0, 0);
    asm volatile("s_waitcnt vmcnt(0)" ::: "memory");
    __builtin_amdgcn_s_barrier();
    for (int t = 0; t < NT; ++t) {
        const int cur = t & 1;
        if (t + 1 < NT) stage((t + 1) << 6, cur ^ 1);
        compute(cur);
        if (t + 1 < NT) {
            asm volatile("s_waitcnt vmcnt(0)" ::: "memory");
            __builtin_amdgcn_s_barrier();
        }
    }

    #pragma unroll
    for (int i = 0; i < 8; ++i) {
        #pragma unroll
        for (int r = 0; r < 4; ++r) {
            const int row = bm + wm * 128 + i * 16 + lc * 4 + r;
            #pragma unroll
            for (int j = 0; j < 4; ++j) {
                const int col = bn + wn * 64 + j * 16 + lr;
                if (col < N) C[(size_t)row * N + col] = acc[i][j][r];
            }
        }
    }
}

// ---------------- BMx128 bf16 MFMA GEMM (layer GEMMs) ----------------
// Proven schedule; BM=128: 64KB LDS, 2 blocks/CU. BM=64: 48KB LDS, 3 blocks/CU.
template<int BM, int OUTF /*0=f32,1=bf16*/, bool GELU, bool RES>
__global__ __launch_bounds__(256)
void gemm_sched(const unsigned short* __restrict__ A, const unsigned short* __restrict__ B,
                const float* __restrict__ bias, const float* __restrict__ res,
                void* __restrict__ Cout, int M, int N, int K) {
    constexpr int ABUF = BM * 64;            // shorts per A buffer
    constexpr int TBUF = (BM + 128) * 64;    // shorts per (A+B) buffer
    __shared__ unsigned short smem[2 * TBUF];
    const int nwg = gridDim.x;
    const int t0 = (blockIdx.x & 7) * (nwg >> 3) + (blockIdx.x >> 3);
    const int MT = M / BM;
    const int NBX = nwg / MT;
    const int srsize = NBX * 8;
    const int sr = t0 / srsize;
    const int rem = t0 - sr * srsize;
    const int bx = rem >> 3;
    const int by = sr * 8 + (rem & 7);
    const int bm = by * BM, bn = bx * 128;
    const int tid = threadIdx.x;
    const int l = tid & 63, w = tid >> 6;
    constexpr int MI = (BM == 128) ? 4 : 2;
    const int wr = (BM == 128) ? (w >> 1) * 64 : (w & 1) * 32;
    const int wc = (BM == 128) ? (w & 1) * 64 : (w >> 1) * 64;
    const int lr = l & 15, lc = l >> 4;
    f32x4 acc[MI][4] = {};

    auto stage = [&](int k0, int buf) {
        #pragma unroll
        for (int p = 0; p < BM * 8 / 256; ++p) {
            int d16 = p * 256 + tid;
            int row = d16 >> 3, cph = d16 & 7;
            int clog = cph ^ (row & 7);
            const unsigned short* ga = A + (size_t)(bm + row) * K + k0 + clog * 8;
            __builtin_amdgcn_global_load_lds(
                (const __attribute__((address_space(1))) unsigned int*)ga,
                (__attribute__((address_space(3))) unsigned int*)(&smem[buf * TBUF + d16 * 8]), 16, 0, 0);
        }
        #pragma unroll
        for (int p = 0; p < 4; ++p) {
            int d16 = p * 256 + tid;
            int row = d16 >> 3, cph = d16 & 7;
            int clog = cph ^ (row & 7);
            const unsigned short* gb = B + (size_t)(bn + row) * K + k0 + clog * 8;
            __builtin_amdgcn_global_load_lds(
                (const __attribute__((address_space(1))) unsigned int*)gb,
                (__attribute__((address_space(3))) unsigned int*)(&smem[buf * TBUF + ABUF + d16 * 8]), 16, 0, 0);
        }
    };

    auto compute = [&](int buf) {
        const unsigned short* Ab = &smem[buf * TBUF];
        const unsigned short* Bb = &smem[buf * TBUF + ABUF];
        #pragma unroll
        for (int ks = 0; ks < 2; ++ks) {
            bf16x8 af[MI], bfr[4];
            #pragma unroll
            for (int mi = 0; mi < MI; ++mi) {
                int row = wr + mi * 16 + lr;
                af[mi] = *reinterpret_cast<const bf16x8*>(
                    &Ab[row * 64 + (((ks * 4 + lc) ^ (row & 7)) * 8)]);
            }
            #pragma unroll
            for (int ni = 0; ni < 4; ++ni) {
                int col = wc + ni * 16 + lr;
                bfr[ni] = *reinterpret_cast<const bf16x8*>(
                    &Bb[col * 64 + (((ks * 4 + lc) ^ (col & 7)) * 8)]);
            }
            __builtin_amdgcn_s_setprio(1);
            #pragma unroll
            for (int mi = 0; mi < MI; ++mi)
                #pragma unroll
                for (int ni = 0; ni < 4; ++ni)
                    acc[mi][ni] = __builtin_amdgcn_mfma_f32_16x16x32_bf16(
                        af[mi], bfr[ni], acc[mi][ni], 0, 0, 0);
            __builtin_amdgcn_s_setprio(0);
        }
    };

    const int NT = K >> 6;
    stage(0, 0);
    asm volatile("s_waitcnt vmcnt(0)" ::: "memory");
    __builtin_amdgcn_s_barrier();
    for (int t = 0; t < NT; ++t) {
        const int cur = t & 1;
        if (t + 1 < NT) stage((t + 1) << 6, cur ^ 1);
        compute(cur);
        if (t + 1 < NT) {
            asm volatile("s_waitcnt vmcnt(0)" ::: "memory");
            __builtin_amdgcn_s_barrier();
        }
    }

    #pragma unroll
    for (int mi = 0; mi < MI; ++mi) {
        #pragma unroll
        for (int r = 0; r < 4; ++r) {
            const int row = bm + wr + mi * 16 + lc * 4 + r;
            #pragma unroll
            for (int ni = 0; ni < 4; ++ni) {
                const int col = bn + wc + ni * 16 + lr;
                float v = acc[mi][ni][r];
                if (bias) v += bias[col];
                if (GELU) v = 0.5f * v * (1.0f + erff(v * 0.70710678118654752f));
                if (RES)  v += res[(size_t)row * N + col];
                if (OUTF == 0) ((float*)Cout)[(size_t)row * N + col] = v;
                else ((unsigned short*)Cout)[(size_t)row * N + col] = f2bf(v);
            }
        }
    }
}

// ---------------- bf16 MFMA causal flash attention (128 q-rows/block) ----------------
// 512 threads = 8 waves x 16 q-rows. KV tile = 32 rows staged once per block.
__global__ __launch_bounds__(512)
void attn_mfma(const unsigned short* __restrict__ qkv, unsigned short* __restrict__ ao) {
    const int qt = gridDim.x - 1 - blockIdx.x;   // heavy blocks first
    const int h = blockIdx.y, b = blockIdx.z;
    const int tid = threadIdx.x;
    const int w = tid >> 6, l = tid & 63;
    const int c = l & 15, g = l >> 4;

    __shared__ unsigned short Ks[32 * 64];       // row-major, 16B-chunk XOR swizzle
    __shared__ unsigned short Vt[64 * 40];       // [d][krow], pad to 40 halves
    __shared__ unsigned int   Ps[8][16 * 20];    // per-wave P transpose

    const unsigned short* base = qkv + (size_t)(b * SEQ) * DQKV + h * HEAD;
    const int q0 = qt * 128 + w * 16;

    bf16x8 qf[2];
    {
        const unsigned short* qp = base + (size_t)(q0 + c) * DQKV + g * 8;
        qf[0] = *reinterpret_cast<const bf16x8*>(qp);
        qf[1] = *reinterpret_cast<const bf16x8*>(qp + 32);
    }

    f32x4 o_acc[4] = {};
    float m_run[4]  = {-INFINITY, -INFINITY, -INFINITY, -INFINITY};
    float l_run[4]  = {0.f, 0.f, 0.f, 0.f};

    // K staging: 512 threads x 8B; row = tid>>4, 8B-chunk = tid&15
    const int srow = tid >> 4, sch8 = tid & 15;
    const int scj = sch8 >> 1, sh = sch8 & 1;
    // V staging: d = tid&63, k-group = tid>>6 (4 rows each)
    const int vd = tid & 63, vw = tid >> 6;

    const int nkt = 4 * qt + 4;
    for (int kt = 0; kt < nkt; ++kt) {
        {
            const unsigned short* kp = base + (size_t)(kt * 32 + srow) * DQKV + 768 + sch8 * 4;
            u16x4 kv = *reinterpret_cast<const u16x4*>(kp);
            *reinterpret_cast<u16x4*>(&Ks[srow * 64 + ((scj ^ (srow & 7)) * 8) + sh * 4]) = kv;
        }
        {
            unsigned short vv[4];
            #pragma unroll
            for (int j = 0; j < 4; ++j)
                vv[j] = base[(size_t)(kt * 32 + vw * 4 + j) * DQKV + 1536 + vd];
            uint2 pk;
            pk.x = vv[0] | ((unsigned)vv[1] << 16);
            pk.y = vv[2] | ((unsigned)vv[3] << 16);
            *reinterpret_cast<uint2*>(&Vt[vd * 40 + vw * 4]) = pk;
        }
        __syncthreads();

        f32x4 s_acc[2] = {};
        #pragma unroll
        for (int t = 0; t < 2; ++t) {
            const int kr = t * 16 + c;
            #pragma unroll
            for (int ks = 0; ks < 2; ++ks) {
                bf16x8 kf = *reinterpret_cast<const bf16x8*>(
                    &Ks[kr * 64 + (((ks * 4 + g) ^ (kr & 7)) * 8)]);
                s_acc[t] = __builtin_amdgcn_mfma_f32_16x16x32_bf16(qf[ks], kf, s_acc[t], 0, 0, 0);
            }
        }
        float sc[2][4];
        #pragma unroll
        for (int t = 0; t < 2; ++t) {
            const int kglob = kt * 32 + t * 16 + c;
            #pragma unroll
            for (int r = 0; r < 4; ++r) {
                float v = s_acc[t][r] * 0.125f;
                sc[t][r] = (kglob > q0 + g * 4 + r) ? -1e30f : v;
            }
        }
        float pout[2][4];
        #pragma unroll
        for (int r = 0; r < 4; ++r) {
            float tmax = fmaxf(sc[0][r], sc[1][r]);
            #pragma unroll
            for (int ms = 1; ms < 16; ms <<= 1) tmax = fmaxf(tmax, __shfl_xor(tmax, ms));
            float mnew = fmaxf(m_run[r], tmax);
            float alpha = __expf(m_run[r] - mnew);
            float p0 = __expf(sc[0][r] - mnew);
            float p1 = __expf(sc[1][r] - mnew);
            float psum = p0 + p1;
            #pragma unroll
            for (int ms = 1; ms < 16; ms <<= 1) psum += __shfl_xor(psum, ms);
            l_run[r] = l_run[r] * alpha + psum;
            m_run[r] = mnew;
            #pragma unroll
            for (int dt = 0; dt < 4; ++dt) o_acc[dt][r] *= alpha;
            pout[0][r] = p0; pout[1][r] = p1;
        }
        #pragma unroll
        for (int t = 0; t < 2; ++t) {
            #pragma unroll
            for (int r = 0; r < 4; ++r) {
                int my = f2bf(pout[t][r]);
                int part = __shfl_xor(my, 1);
                unsigned int word = (c & 1) ? ((unsigned)(part & 0xffff) | ((unsigned)my << 16))
                                            : ((unsigned)(my & 0xffff) | ((unsigned)part << 16));
                Ps[w][(g * 4 + r) * 20 + t * 8 + (c >> 1)] = word;
            }
        }
        uint4 praw = *reinterpret_cast<const uint4*>(&Ps[w][c * 20 + g * 4]);
        bf16x8 pf = *reinterpret_cast<const bf16x8*>(&praw);
        #pragma unroll
        for (int dt = 0; dt < 4; ++dt) {
            bf16x8 vf = *reinterpret_cast<const bf16x8*>(&Vt[(dt * 16 + c) * 40 + g * 8]);
            o_acc[dt] = __builtin_amdgcn_mfma_f32_16x16x32_bf16(pf, vf, o_acc[dt], 0, 0, 0);
        }
        __syncthreads();
    }

    float inv[4];
    #pragma unroll
    for (int r = 0; r < 4; ++r) inv[r] = 1.0f / l_run[r];
    #pragma unroll
    for (int r = 0; r < 4; ++r) {
        unsigned short* op = ao + (size_t)(b * SEQ + q0 + g * 4 + r) * D_MODEL + h * HEAD + c;
        #pragma unroll
        for (int dt = 0; dt < 4; ++dt)
            op[dt * 16] = f2bf(o_acc[dt][r] * inv[r]);
    }
}

extern "C" void kernel_launch(void* const* d_in, const int* in_sizes, int n_in,
                              void* d_out, int out_size, void* d_ws, size_t ws_size,
                              hipStream_t stream) {
    const int*   idx     = (const int*)  d_in[0];
    const float* tok_emb = (const float*)d_in[1];
    const float* pos_emb = (const float*)d_in[2];
    const float* Wq      = (const float*)d_in[3];
    const float* bq      = (const float*)d_in[4];
    const float* Wk      = (const float*)d_in[5];
    const float* bk      = (const float*)d_in[6];
    const float* Wv      = (const float*)d_in[7];
    const float* bv      = (const float*)d_in[8];
    const float* Wproj   = (const float*)d_in[9];
    const float* bproj   = (const float*)d_in[10];
    const float* ln1g    = (const float*)d_in[11];
    const float* ln1b    = (const float*)d_in[12];
    const float* ln2g    = (const float*)d_in[13];
    const float* ln2b    = (const float*)d_in[14];
    const float* Wf1     = (const float*)d_in[15];
    const float* bf1     = (const float*)d_in[16];
    const float* Wf2     = (const float*)d_in[17];
    const float* bf2     = (const float*)d_in[18];
    const float* lnfg    = (const float*)d_in[19];
    const float* lnfb    = (const float*)d_in[20];
    const float* Wlm     = (const float*)d_in[21];
    float* outp = (float*)d_out;

    char* basep = (char*)d_ws;
    size_t off = 0;
    auto alloc = [&](size_t bytes) -> void* {
        void* p = basep + off;
        off = (off + bytes + 255) & ~(size_t)255;
        return p;
    };
    float*          x      = (float*)         alloc((size_t)NROWS * D_MODEL * 4);
    unsigned short* qkv    = (unsigned short*)alloc((size_t)NROWS * DQKV * 2);
    unsigned short* hb     = (unsigned short*)alloc((size_t)NROWS * D_MODEL * 2);
    unsigned short* ao     = (unsigned short*)alloc((size_t)NROWS * D_MODEL * 2);
    unsigned short* mid    = (unsigned short*)alloc((size_t)NROWS * DFFN * 2);
    unsigned short* Wqkvb  = (unsigned short*)alloc((size_t)NLAYER * DQKV * D_MODEL * 2);
    unsigned short* Wprojb = (unsigned short*)alloc((size_t)NLAYER * D_MODEL * D_MODEL * 2);
    unsigned short* Wf1b   = (unsigned short*)alloc((size_t)NLAYER * DFFN * D_MODEL * 2);
    unsigned short* Wf2b   = (unsigned short*)alloc((size_t)NLAYER * D_MODEL * DFFN * 2);
    unsigned short* Wlmb   = (unsigned short*)alloc((size_t)VPAD * D_MODEL * 2);
    float*          bqkv   = (float*)         alloc((size_t)NLAYER * DQKV * 4);

    dim3 blk(256);
    dim3 tblk(32, 8);

    conv_lm<<<2048, blk, 0, stream>>>(Wlm, Wlmb);
    conv_transpose<1><<<dim3(24, 24, 6), tblk, 0, stream>>>(Wq, Wqkvb,             768, 768,  (size_t)768*768,  (size_t)DQKV*768);
    conv_transpose<1><<<dim3(24, 24, 6), tblk, 0, stream>>>(Wk, Wqkvb + 768*768,   768, 768,  (size_t)768*768,  (size_t)DQKV*768);
    conv_transpose<1><<<dim3(24, 24, 6), tblk, 0, stream>>>(Wv, Wqkvb + 2*768*768, 768, 768,  (size_t)768*768,  (size_t)DQKV*768);
    conv_transpose<0><<<dim3(24, 24, 6), tblk, 0, stream>>>(Wproj, Wprojb,         768, 768,  (size_t)768*768,  (size_t)768*768);
    conv_transpose<0><<<dim3(96, 24, 6), tblk, 0, stream>>>(Wf1, Wf1b,             768, 3072, (size_t)768*3072, (size_t)3072*768);
    conv_transpose<0><<<dim3(24, 96, 6), tblk, 0, stream>>>(Wf2, Wf2b,             3072, 768, (size_t)3072*768, (size_t)768*3072);
    conv_bias<<<(NLAYER * DQKV + 255) / 256, blk, 0, stream>>>(bq, bk, bv, bqkv);

    embed_kernel<<<NROWS, blk, 0, stream>>>(idx, tok_emb, pos_emb, x);

    dim3 gqkv(32 * 18);                  // BM=128, 576 blocks
    dim3 g768s(64 * 6);                  // BM=64,  384 blocks (proj, FFN2)
    dim3 g3072(32 * 24);                 // BM=128, 768 blocks (FFN1)
    dim3 ga(SEQ / 128, N_HEAD, BATCH);   // (8, 12, 4)

    for (int li = 0; li < NLAYER; ++li) {
        ln_kernel<<<NROWS, blk, 0, stream>>>(x, ln1g + li * D_MODEL, ln1b + li * D_MODEL, hb);

        gemm_sched<128, 1, false, false><<<gqkv, blk, 0, stream>>>(
            hb, Wqkvb + (size_t)li * DQKV * D_MODEL, bqkv + li * DQKV, nullptr,
            qkv, NROWS, DQKV, D_MODEL);

        attn_mfma<<<ga, dim3(512), 0, stream>>>(qkv, ao);

        gemm_sched<64, 0, false, true><<<g768s, blk, 0, stream>>>(
            ao, Wprojb + (size_t)li * D_MODEL * D_MODEL, bproj + li * D_MODEL, x,
            x, NROWS, D_MODEL, D_MODEL);

        ln_kernel<<<NROWS, blk, 0, stream>>>(x, ln2g + li * D_MODEL, ln2b + li * D_MODEL, hb);

        gemm_sched<128, 1, true, false><<<g3072, blk, 0, stream>>>(
            hb, Wf1b + (size_t)li * DFFN * D_MODEL, bf1 + li * DFFN, nullptr,
            mid, NROWS, DFFN, D_MODEL);

        gemm_sched<64, 0, false, true><<<g768s, blk, 0, stream>>>(
            mid, Wf2b + (size_t)li * D_MODEL * DFFN, bf2 + li * D_MODEL, x,
            x, NROWS, D_MODEL, DFFN);
    }

    ln_kernel<<<NROWS, blk, 0, stream>>>(x, lnfg, lnfb, hb);

    dim3 gl((VPAD / 256) * (NROWS / 256));   // 197 * 16 = 3152 blocks
    gemm256_mfma<<<gl, dim3(512), 0, stream>>>(hb, Wlmb, outp, NROWS, VOCAB, D_MODEL);
}

// Round 10
// 2122.414 us; speedup vs baseline: 1.4983x; 1.0681x over previous
//
#include <hip/hip_runtime.h>
#include <hip/hip_bf16.h>
#include <math.h>

#define D_MODEL 768
#define N_HEAD  12
#define HEAD    64
#define SEQ     1024
#define NLAYER  6
#define BATCH   4
#define NROWS   (BATCH*SEQ)   // 4096
#define VOCAB   50257
#define VPAD    50432         // 197*256
#define DFFN    3072
#define DQKV    2304

typedef __attribute__((ext_vector_type(8))) __bf16 bf16x8;
typedef __attribute__((ext_vector_type(4))) float f32x4;
typedef __attribute__((ext_vector_type(4))) unsigned short u16x4;
typedef __attribute__((ext_vector_type(8))) unsigned short u16x8;

__device__ inline unsigned short f2bf(float x) {
    __hip_bfloat16 h = __float2bfloat16(x);
    return *reinterpret_cast<unsigned short*>(&h);
}

// ---------------- embedding ----------------
__global__ __launch_bounds__(256)
void embed_kernel(const int* __restrict__ idx, const float* __restrict__ tok,
                  const float* __restrict__ pos, float* __restrict__ x) {
    int row = blockIdx.x;
    int t = idx[row];
    int s = row & (SEQ - 1);
    const float* tp = tok + (size_t)t * D_MODEL;
    const float* pp = pos + (size_t)s * D_MODEL;
    float* xp = x + (size_t)row * D_MODEL;
    for (int i = threadIdx.x; i < D_MODEL; i += 256) xp[i] = tp[i] + pp[i];
}

// ---------------- layernorm: fp32 in, bf16 out ----------------
__global__ __launch_bounds__(256)
void ln_kernel(const float* __restrict__ in, const float* __restrict__ gw,
               const float* __restrict__ bw, unsigned short* __restrict__ out) {
    int row = blockIdx.x;
    int tid = threadIdx.x;
    const float* x = in + (size_t)row * D_MODEL;
    float v0 = x[tid], v1 = x[tid + 256], v2 = x[tid + 512];
    float s  = v0 + v1 + v2;
    float sq = v0*v0 + v1*v1 + v2*v2;
    #pragma unroll
    for (int o = 1; o < 64; o <<= 1) { s += __shfl_xor(s, o); sq += __shfl_xor(sq, o); }
    __shared__ float red[8];
    int wave = tid >> 6;
    if ((tid & 63) == 0) { red[wave] = s; red[4 + wave] = sq; }
    __syncthreads();
    s  = red[0] + red[1] + red[2] + red[3];
    sq = red[4] + red[5] + red[6] + red[7];
    float mean = s * (1.0f / D_MODEL);
    float var  = sq * (1.0f / D_MODEL) - mean * mean;
    float rstd = rsqrtf(var + 1e-5f);
    unsigned short* op = out + (size_t)row * D_MODEL;
    op[tid]       = f2bf((v0 - mean) * rstd * gw[tid]       + bw[tid]);
    op[tid + 256] = f2bf((v1 - mean) * rstd * gw[tid + 256] + bw[tid + 256]);
    op[tid + 512] = f2bf((v2 - mean) * rstd * gw[tid + 512] + bw[tid + 512]);
}

// ---------------- weight conversion (vectorized: float4 in, 16B out) ----------------
// 64x64 tile; MODE 0: in[k*N+n]; MODE 1 (per-head, n0%64==0): head = n0>>6
template<int MODE>
__global__ __launch_bounds__(256)
void conv_transpose(const float* __restrict__ in, unsigned short* __restrict__ out,
                    int K, int N, size_t inLstride, size_t outLstride) {
    __shared__ float t[64][65];
    const int tid = threadIdx.x;
    const int n0 = blockIdx.x * 64, k0 = blockIdx.y * 64;
    const float* ip = in + blockIdx.z * inLstride;
    unsigned short* op = out + blockIdx.z * outLstride;
    {
        const int kk = tid >> 4, nq = tid & 15;
        #pragma unroll
        for (int p = 0; p < 4; ++p) {
            int k = kk + p * 16;
            float4 v;
            if (MODE == 0) v = *reinterpret_cast<const float4*>(&ip[(size_t)(k0 + k) * N + n0 + nq * 4]);
            else           v = *reinterpret_cast<const float4*>(&ip[((size_t)(n0 >> 6) * K + (k0 + k)) * 64 + nq * 4]);
            t[k][nq * 4 + 0] = v.x; t[k][nq * 4 + 1] = v.y;
            t[k][nq * 4 + 2] = v.z; t[k][nq * 4 + 3] = v.w;
        }
    }
    __syncthreads();
    {
        const int n = tid >> 2, kq = tid & 3;
        unsigned short buf[16];
        #pragma unroll
        for (int j = 0; j < 16; ++j) buf[j] = f2bf(t[kq * 16 + j][n]);
        unsigned short* dst = &op[(size_t)(n0 + n) * K + k0 + kq * 16];
        *reinterpret_cast<u16x8*>(dst)     = *reinterpret_cast<u16x8*>(&buf[0]);
        *reinterpret_cast<u16x8*>(dst + 8) = *reinterpret_cast<u16x8*>(&buf[8]);
    }
}

__global__ __launch_bounds__(256)
void conv_lm(const float* __restrict__ in, unsigned short* __restrict__ out) {
    const int nchunks = VPAD * D_MODEL / 4;
    const int vchunks = VOCAB * D_MODEL / 4;
    for (int i = blockIdx.x * 256 + threadIdx.x; i < nchunks; i += gridDim.x * 256) {
        u16x4 o;
        if (i < vchunks) {
            float4 v = reinterpret_cast<const float4*>(in)[i];
            o[0] = f2bf(v.x); o[1] = f2bf(v.y); o[2] = f2bf(v.z); o[3] = f2bf(v.w);
        } else { o[0] = 0; o[1] = 0; o[2] = 0; o[3] = 0; }
        reinterpret_cast<u16x4*>(out)[i] = o;
    }
}

__global__ __launch_bounds__(256)
void conv_bias(const float* __restrict__ bq, const float* __restrict__ bk,
               const float* __restrict__ bv, float* __restrict__ out) {
    int i = blockIdx.x * 256 + threadIdx.x;
    if (i >= NLAYER * DQKV) return;
    int l = i / DQKV, n = i % DQKV;
    float v;
    if (n < 768)        v = bq[l * 768 + n];
    else if (n < 1536)  v = bk[l * 768 + n - 768];
    else                v = bv[l * 768 + n - 1536];
    out[i] = v;
}

// ---------------- 256x256 bf16 MFMA GEMM (logits), BK=32, 2 blocks/CU ----------------
// Issue-early staging, one vmcnt(0)+barrier per K-tile, XOR-swizzle (chunk^=row&3).
// 64 KiB LDS -> 2 blocks/CU so one block's epilogue overlaps the other's K-loop.
__global__ __launch_bounds__(512)
void gemm256_mfma(const unsigned short* __restrict__ A, const unsigned short* __restrict__ B,
                  float* __restrict__ C, int M, int N, int K) {
    __shared__ unsigned short smem[2 * 16384];       // 64 KiB: 2 buf x (A 8192 + B 8192)
    const int nwg = gridDim.x;
    const int t0 = (blockIdx.x & 7) * (nwg >> 3) + (blockIdx.x >> 3);
    const int MT = M >> 8;
    const int NBX = nwg / MT;
    const int srsize = NBX * 8;
    const int sr = t0 / srsize;
    const int rem = t0 - sr * srsize;
    const int bx = rem >> 3;
    const int by = sr * 8 + (rem & 7);
    const int bm = by * 256, bn = bx * 256;
    const int tid = threadIdx.x;
    const int l = tid & 63, w = tid >> 6;
    const int wm = w >> 2, wn = w & 3;
    const int lr = l & 15, lc = l >> 4;
    f32x4 acc[8][4] = {};

    auto stage = [&](int k0, int buf) {
        #pragma unroll
        for (int p = 0; p < 2; ++p) {
            int d16 = p * 512 + tid;                 // 1024 chunks: 256 rows x 4
            int row = d16 >> 2, cph = d16 & 3;
            int clog = cph ^ (row & 3);
            const unsigned short* ga = A + (size_t)(bm + row) * K + k0 + clog * 8;
            __builtin_amdgcn_global_load_lds(
                (const __attribute__((address_space(1))) unsigned int*)ga,
                (__attribute__((address_space(3))) unsigned int*)(&smem[buf * 16384 + d16 * 8]), 16, 0, 0);
        }
        #pragma unroll
        for (int p = 0; p < 2; ++p) {
            int d16 = p * 512 + tid;
            int row = d16 >> 2, cph = d16 & 3;
            int clog = cph ^ (row & 3);
            const unsigned short* gb = B + (size_t)(bn + row) * K + k0 + clog * 8;
            __builtin_amdgcn_global_load_lds(
                (const __attribute__((address_space(1))) unsigned int*)gb,
                (__attribute__((address_space(3))) unsigned int*)(&smem[buf * 16384 + 8192 + d16 * 8]), 16, 0, 0);
        }
    };

    auto compute = [&](int buf) {
        const unsigned short* Ab = &smem[buf * 16384];
        const unsigned short* Bb = &smem[buf * 16384 + 8192];
        #pragma unroll
        for (int qm = 0; qm < 2; ++qm) {
            bf16x8 af[4];
            #pragma unroll
            for (int mi = 0; mi < 4; ++mi) {
                int row = wm * 128 + qm * 64 + mi * 16 + lr;
                af[mi] = *reinterpret_cast<const bf16x8*>(&Ab[row * 32 + ((lc ^ (row & 3)) * 8)]);
            }
            #pragma unroll
            for (int qn = 0; qn < 2; ++qn) {
                bf16x8 bfr[2];
                #pragma unroll
                for (int ni = 0; ni < 2; ++ni) {
                    int col = wn * 64 + qn * 32 + ni * 16 + lr;
                    bfr[ni] = *reinterpret_cast<const bf16x8*>(&Bb[col * 32 + ((lc ^ (col & 3)) * 8)]);
                }
                __builtin_amdgcn_s_setprio(1);
                #pragma unroll
                for (int mi = 0; mi < 4; ++mi)
                    #pragma unroll
                    for (int ni = 0; ni < 2; ++ni)
                        acc[qm * 4 + mi][qn * 2 + ni] = __builtin_amdgcn_mfma_f32_16x16x32_bf16(
                            af[mi], bfr[ni], acc[qm * 4 + mi][qn * 2 + ni], 0, 0, 0);
                __builtin_amdgcn_s_setprio(0);
            }
        }
    };

    const int NT = K >> 5;                           // 24
    stage(0, 0);
    asm volatile("s_waitcnt vmcnt(0)" ::: "memory");
    __builtin_amdgcn_s_barrier();
    for (int t = 0; t < NT; ++t) {
        const int cur = t & 1;
        if (t + 1 < NT) stage((t + 1) << 5, cur ^ 1);
        compute(cur);
        if (t + 1 < NT) {
            asm volatile("s_waitcnt vmcnt(0)" ::: "memory");
            __builtin_amdgcn_s_barrier();
        }
    }

    #pragma unroll
    for (int i = 0; i < 8; ++i) {
        #pragma unroll
        for (int r = 0; r < 4; ++r) {
            const int row = bm + wm * 128 + i * 16 + lc * 4 + r;
            #pragma unroll
            for (int j = 0; j < 4; ++j) {
                const int col = bn + wn * 64 + j * 16 + lr;
                if (col < N) C[(size_t)row * N + col] = acc[i][j][r];
            }
        }
    }
}

// ---------------- BMx128 bf16 MFMA GEMM (layer GEMMs) ----------------
// Swapped-operand MFMA: lane holds 4 CONSECUTIVE COLS -> float4/u16x4 epilogue.
// BM=128: 64KB LDS, 2 blocks/CU. BM=64: 48KB LDS, 3 blocks/CU.
template<int BM, int OUTF /*0=f32,1=bf16*/, bool GELU, bool RES>
__global__ __launch_bounds__(256)
void gemm_sched(const unsigned short* __restrict__ A, const unsigned short* __restrict__ B,
                const float* __restrict__ bias, const float* __restrict__ res,
                void* __restrict__ Cout, int M, int N, int K) {
    constexpr int ABUF = BM * 64;            // shorts per A buffer
    constexpr int TBUF = (BM + 128) * 64;    // shorts per (A+B) buffer
    __shared__ unsigned short smem[2 * TBUF];
    const int nwg = gridDim.x;
    const int t0 = (blockIdx.x & 7) * (nwg >> 3) + (blockIdx.x >> 3);
    const int MT = M / BM;
    const int NBX = nwg / MT;
    const int srsize = NBX * 8;
    const int sr = t0 / srsize;
    const int rem = t0 - sr * srsize;
    const int bx = rem >> 3;
    const int by = sr * 8 + (rem & 7);
    const int bm = by * BM, bn = bx * 128;
    const int tid = threadIdx.x;
    const int l = tid & 63, w = tid >> 6;
    constexpr int MI = (BM == 128) ? 4 : 2;
    const int wr = (BM == 128) ? (w >> 1) * 64 : (w & 1) * 32;
    const int wc = (BM == 128) ? (w & 1) * 64 : (w >> 1) * 64;
    const int lr = l & 15, lc = l >> 4;
    f32x4 acc[MI][4] = {};

    auto stage = [&](int k0, int buf) {
        #pragma unroll
        for (int p = 0; p < BM * 8 / 256; ++p) {
            int d16 = p * 256 + tid;
            int row = d16 >> 3, cph = d16 & 7;
            int clog = cph ^ (row & 7);
            const unsigned short* ga = A + (size_t)(bm + row) * K + k0 + clog * 8;
            __builtin_amdgcn_global_load_lds(
                (const __attribute__((address_space(1))) unsigned int*)ga,
                (__attribute__((address_space(3))) unsigned int*)(&smem[buf * TBUF + d16 * 8]), 16, 0, 0);
        }
        #pragma unroll
        for (int p = 0; p < 4; ++p) {
            int d16 = p * 256 + tid;
            int row = d16 >> 3, cph = d16 & 7;
            int clog = cph ^ (row & 7);
            const unsigned short* gb = B + (size_t)(bn + row) * K + k0 + clog * 8;
            __builtin_amdgcn_global_load_lds(
                (const __attribute__((address_space(1))) unsigned int*)gb,
                (__attribute__((address_space(3))) unsigned int*)(&smem[buf * TBUF + ABUF + d16 * 8]), 16, 0, 0);
        }
    };

    auto compute = [&](int buf) {
        const unsigned short* Ab = &smem[buf * TBUF];
        const unsigned short* Bb = &smem[buf * TBUF + ABUF];
        #pragma unroll
        for (int ks = 0; ks < 2; ++ks) {
            bf16x8 af[MI], bfr[4];
            #pragma unroll
            for (int mi = 0; mi < MI; ++mi) {
                int row = wr + mi * 16 + lr;
                af[mi] = *reinterpret_cast<const bf16x8*>(
                    &Ab[row * 64 + (((ks * 4 + lc) ^ (row & 7)) * 8)]);
            }
            #pragma unroll
            for (int ni = 0; ni < 4; ++ni) {
                int col = wc + ni * 16 + lr;
                bfr[ni] = *reinterpret_cast<const bf16x8*>(
                    &Bb[col * 64 + (((ks * 4 + lc) ^ (col & 7)) * 8)]);
            }
            __builtin_amdgcn_s_setprio(1);
            #pragma unroll
            for (int mi = 0; mi < MI; ++mi)
                #pragma unroll
                for (int ni = 0; ni < 4; ++ni)
                    acc[mi][ni] = __builtin_amdgcn_mfma_f32_16x16x32_bf16(
                        bfr[ni], af[mi], acc[mi][ni], 0, 0, 0);   // SWAPPED: D = B^T-tile x A-tile
            __builtin_amdgcn_s_setprio(0);
        }
    };

    const int NT = K >> 6;
    stage(0, 0);
    asm volatile("s_waitcnt vmcnt(0)" ::: "memory");
    __builtin_amdgcn_s_barrier();
    for (int t = 0; t < NT; ++t) {
        const int cur = t & 1;
        if (t + 1 < NT) stage((t + 1) << 6, cur ^ 1);
        compute(cur);
        if (t + 1 < NT) {
            asm volatile("s_waitcnt vmcnt(0)" ::: "memory");
            __builtin_amdgcn_s_barrier();
        }
    }

    // swapped C/D mapping: C-row = lr, C-col = lc*4 + r  (4 consecutive cols/lane)
    #pragma unroll
    for (int mi = 0; mi < MI; ++mi) {
        const int row = bm + wr + mi * 16 + lr;
        #pragma unroll
        for (int ni = 0; ni < 4; ++ni) {
            const int colb = bn + wc + ni * 16 + lc * 4;
            f32x4 v = acc[mi][ni];
            if (bias) v += *reinterpret_cast<const f32x4*>(&bias[colb]);
            if (GELU) {
                #pragma unroll
                for (int r = 0; r < 4; ++r)
                    v[r] = 0.5f * v[r] * (1.0f + erff(v[r] * 0.70710678118654752f));
            }
            if (RES) v += *reinterpret_cast<const f32x4*>(&res[(size_t)row * N + colb]);
            if (OUTF == 0) {
                *reinterpret_cast<f32x4*>(&((float*)Cout)[(size_t)row * N + colb]) = v;
            } else {
                u16x4 o;
                o[0] = f2bf(v[0]); o[1] = f2bf(v[1]); o[2] = f2bf(v[2]); o[3] = f2bf(v[3]);
                *reinterpret_cast<u16x4*>(&((unsigned short*)Cout)[(size_t)row * N + colb]) = o;
            }
        }
    }
}

// ---------------- bf16 MFMA causal flash attention (128 q-rows/block) ----------------
__global__ __launch_bounds__(512)
void attn_mfma(const unsigned short* __restrict__ qkv, unsigned short* __restrict__ ao) {
    const int qt = gridDim.x - 1 - blockIdx.x;   // heavy blocks first
    const int h = blockIdx.y, b = blockIdx.z;
    const int tid = threadIdx.x;
    const int w = tid >> 6, l = tid & 63;
    const int c = l & 15, g = l >> 4;

    __shared__ unsigned short Ks[32 * 64];
    __shared__ unsigned short Vt[64 * 40];
    __shared__ unsigned int   Ps[8][16 * 20];

    const unsigned short* base = qkv + (size_t)(b * SEQ) * DQKV + h * HEAD;
    const int q0 = qt * 128 + w * 16;

    bf16x8 qf[2];
    {
        const unsigned short* qp = base + (size_t)(q0 + c) * DQKV + g * 8;
        qf[0] = *reinterpret_cast<const bf16x8*>(qp);
        qf[1] = *reinterpret_cast<const bf16x8*>(qp + 32);
    }

    f32x4 o_acc[4] = {};
    float m_run[4]  = {-INFINITY, -INFINITY, -INFINITY, -INFINITY};
    float l_run[4]  = {0.f, 0.f, 0.f, 0.f};

    const int srow = tid >> 4, sch8 = tid & 15;
    const int scj = sch8 >> 1, sh = sch8 & 1;
    const int vd = tid & 63, vw = tid >> 6;

    const int nkt = 4 * qt + 4;
    for (int kt = 0; kt < nkt; ++kt) {
        {
            const unsigned short* kp = base + (size_t)(kt * 32 + srow) * DQKV + 768 + sch8 * 4;
            u16x4 kv = *reinterpret_cast<const u16x4*>(kp);
            *reinterpret_cast<u16x4*>(&Ks[srow * 64 + ((scj ^ (srow & 7)) * 8) + sh * 4]) = kv;
        }
        {
            unsigned short vv[4];
            #pragma unroll
            for (int j = 0; j < 4; ++j)
                vv[j] = base[(size_t)(kt * 32 + vw * 4 + j) * DQKV + 1536 + vd];
            uint2 pk;
            pk.x = vv[0] | ((unsigned)vv[1] << 16);
            pk.y = vv[2] | ((unsigned)vv[3] << 16);
            *reinterpret_cast<uint2*>(&Vt[vd * 40 + vw * 4]) = pk;
        }
        __syncthreads();

        f32x4 s_acc[2] = {};
        #pragma unroll
        for (int t = 0; t < 2; ++t) {
            const int kr = t * 16 + c;
            #pragma unroll
            for (int ks = 0; ks < 2; ++ks) {
                bf16x8 kf = *reinterpret_cast<const bf16x8*>(
                    &Ks[kr * 64 + (((ks * 4 + g) ^ (kr & 7)) * 8)]);
                s_acc[t] = __builtin_amdgcn_mfma_f32_16x16x32_bf16(qf[ks], kf, s_acc[t], 0, 0, 0);
            }
        }
        float sc[2][4];
        #pragma unroll
        for (int t = 0; t < 2; ++t) {
            const int kglob = kt * 32 + t * 16 + c;
            #pragma unroll
            for (int r = 0; r < 4; ++r) {
                float v = s_acc[t][r] * 0.125f;
                sc[t][r] = (kglob > q0 + g * 4 + r) ? -1e30f : v;
            }
        }
        float pout[2][4];
        #pragma unroll
        for (int r = 0; r < 4; ++r) {
            float tmax = fmaxf(sc[0][r], sc[1][r]);
            #pragma unroll
            for (int ms = 1; ms < 16; ms <<= 1) tmax = fmaxf(tmax, __shfl_xor(tmax, ms));
            float mnew = fmaxf(m_run[r], tmax);
            float alpha = __expf(m_run[r] - mnew);
            float p0 = __expf(sc[0][r] - mnew);
            float p1 = __expf(sc[1][r] - mnew);
            float psum = p0 + p1;
            #pragma unroll
            for (int ms = 1; ms < 16; ms <<= 1) psum += __shfl_xor(psum, ms);
            l_run[r] = l_run[r] * alpha + psum;
            m_run[r] = mnew;
            #pragma unroll
            for (int dt = 0; dt < 4; ++dt) o_acc[dt][r] *= alpha;
            pout[0][r] = p0; pout[1][r] = p1;
        }
        #pragma unroll
        for (int t = 0; t < 2; ++t) {
            #pragma unroll
            for (int r = 0; r < 4; ++r) {
                int my = f2bf(pout[t][r]);
                int part = __shfl_xor(my, 1);
                unsigned int word = (c & 1) ? ((unsigned)(part & 0xffff) | ((unsigned)my << 16))
                                            : ((unsigned)(my & 0xffff) | ((unsigned)part << 16));
                Ps[w][(g * 4 + r) * 20 + t * 8 + (c >> 1)] = word;
            }
        }
        uint4 praw = *reinterpret_cast<const uint4*>(&Ps[w][c * 20 + g * 4]);
        bf16x8 pf = *reinterpret_cast<const bf16x8*>(&praw);
        #pragma unroll
        for (int dt = 0; dt < 4; ++dt) {
            bf16x8 vf = *reinterpret_cast<const bf16x8*>(&Vt[(dt * 16 + c) * 40 + g * 8]);
            o_acc[dt] = __builtin_amdgcn_mfma_f32_16x16x32_bf16(pf, vf, o_acc[dt], 0, 0, 0);
        }
        __syncthreads();
    }

    float inv[4];
    #pragma unroll
    for (int r = 0; r < 4; ++r) inv[r] = 1.0f / l_run[r];
    #pragma unroll
    for (int r = 0; r < 4; ++r) {
        unsigned short* op = ao + (size_t)(b * SEQ + q0 + g * 4 + r) * D_MODEL + h * HEAD + c;
        #pragma unroll
        for (int dt = 0; dt < 4; ++dt)
            op[dt * 16] = f2bf(o_acc[dt][r] * inv[r]);
    }
}

extern "C" void kernel_launch(void* const* d_in, const int* in_sizes, int n_in,
                              void* d_out, int out_size, void* d_ws, size_t ws_size,
                              hipStream_t stream) {
    const int*   idx     = (const int*)  d_in[0];
    const float* tok_emb = (const float*)d_in[1];
    const float* pos_emb = (const float*)d_in[2];
    const float* Wq      = (const float*)d_in[3];
    const float* bq      = (const float*)d_in[4];
    const float* Wk      = (const float*)d_in[5];
    const float* bk      = (const float*)d_in[6];
    const float* Wv      = (const float*)d_in[7];
    const float* bv      = (const float*)d_in[8];
    const float* Wproj   = (const float*)d_in[9];
    const float* bproj   = (const float*)d_in[10];
    const float* ln1g    = (const float*)d_in[11];
    const float* ln1b    = (const float*)d_in[12];
    const float* ln2g    = (const float*)d_in[13];
    const float* ln2b    = (const float*)d_in[14];
    const float* Wf1     = (const float*)d_in[15];
    const float* bf1     = (const float*)d_in[16];
    const float* Wf2     = (const float*)d_in[17];
    const float* bf2     = (const float*)d_in[18];
    const float* lnfg    = (const float*)d_in[19];
    const float* lnfb    = (const float*)d_in[20];
    const float* Wlm     = (const float*)d_in[21];
    float* outp = (float*)d_out;

    char* basep = (char*)d_ws;
    size_t off = 0;
    auto alloc = [&](size_t bytes) -> void* {
        void* p = basep + off;
        off = (off + bytes + 255) & ~(size_t)255;
        return p;
    };
    float*          x      = (float*)         alloc((size_t)NROWS * D_MODEL * 4);
    unsigned short* qkv    = (unsigned short*)alloc((size_t)NROWS * DQKV * 2);
    unsigned short* hb     = (unsigned short*)alloc((size_t)NROWS * D_MODEL * 2);
    unsigned short* ao     = (unsigned short*)alloc((size_t)NROWS * D_MODEL * 2);
    unsigned short* mid    = (unsigned short*)alloc((size_t)NROWS * DFFN * 2);
    unsigned short* Wqkvb  = (unsigned short*)alloc((size_t)NLAYER * DQKV * D_MODEL * 2);
    unsigned short* Wprojb = (unsigned short*)alloc((size_t)NLAYER * D_MODEL * D_MODEL * 2);
    unsigned short* Wf1b   = (unsigned short*)alloc((size_t)NLAYER * DFFN * D_MODEL * 2);
    unsigned short* Wf2b   = (unsigned short*)alloc((size_t)NLAYER * D_MODEL * DFFN * 2);
    unsigned short* Wlmb   = (unsigned short*)alloc((size_t)VPAD * D_MODEL * 2);
    float*          bqkv   = (float*)         alloc((size_t)NLAYER * DQKV * 4);

    dim3 blk(256);

    conv_lm<<<2048, blk, 0, stream>>>(Wlm, Wlmb);
    conv_transpose<1><<<dim3(12, 12, 6), blk, 0, stream>>>(Wq, Wqkvb,             768, 768,  (size_t)768*768,  (size_t)DQKV*768);
    conv_transpose<1><<<dim3(12, 12, 6), blk, 0, stream>>>(Wk, Wqkvb + 768*768,   768, 768,  (size_t)768*768,  (size_t)DQKV*768);
    conv_transpose<1><<<dim3(12, 12, 6), blk, 0, stream>>>(Wv, Wqkvb + 2*768*768, 768, 768,  (size_t)768*768,  (size_t)DQKV*768);
    conv_transpose<0><<<dim3(12, 12, 6), blk, 0, stream>>>(Wproj, Wprojb,         768, 768,  (size_t)768*768,  (size_t)768*768);
    conv_transpose<0><<<dim3(48, 12, 6), blk, 0, stream>>>(Wf1, Wf1b,             768, 3072, (size_t)768*3072, (size_t)3072*768);
    conv_transpose<0><<<dim3(12, 48, 6), blk, 0, stream>>>(Wf2, Wf2b,             3072, 768, (size_t)3072*768, (size_t)768*3072);
    conv_bias<<<(NLAYER * DQKV + 255) / 256, blk, 0, stream>>>(bq, bk, bv, bqkv);

    embed_kernel<<<NROWS, blk, 0, stream>>>(idx, tok_emb, pos_emb, x);

    dim3 gqkv(32 * 18);                  // BM=128, 576 blocks
    dim3 g768s(64 * 6);                  // BM=64,  384 blocks (proj, FFN2)
    dim3 g3072(32 * 24);                 // BM=128, 768 blocks (FFN1)
    dim3 ga(SEQ / 128, N_HEAD, BATCH);   // (8, 12, 4)

    for (int li = 0; li < NLAYER; ++li) {
        ln_kernel<<<NROWS, blk, 0, stream>>>(x, ln1g + li * D_MODEL, ln1b + li * D_MODEL, hb);

        gemm_sched<128, 1, false, false><<<gqkv, blk, 0, stream>>>(
            hb, Wqkvb + (size_t)li * DQKV * D_MODEL, bqkv + li * DQKV, nullptr,
            qkv, NROWS, DQKV, D_MODEL);

        attn_mfma<<<ga, dim3(512), 0, stream>>>(qkv, ao);

        gemm_sched<64, 0, false, true><<<g768s, blk, 0, stream>>>(
            ao, Wprojb + (size_t)li * D_MODEL * D_MODEL, bproj + li * D_MODEL, x,
            x, NROWS, D_MODEL, D_MODEL);

        ln_kernel<<<NROWS, blk, 0, stream>>>(x, ln2g + li * D_MODEL, ln2b + li * D_MODEL, hb);

        gemm_sched<128, 1, true, false><<<g3072, blk, 0, stream>>>(
            hb, Wf1b + (size_t)li * DFFN * D_MODEL, bf1 + li * DFFN, nullptr,
            mid, NROWS, DFFN, D_MODEL);

        gemm_sched<64, 0, false, true><<<g768s, blk, 0, stream>>>(
            mid, Wf2b + (size_t)li * D_MODEL * DFFN, bf2 + li * D_MODEL, x,
            x, NROWS, D_MODEL, DFFN);
    }

    ln_kernel<<<NROWS, blk, 0, stream>>>(x, lnfg, lnfb, hb);

    dim3 gl((VPAD / 256) * (NROWS / 256));   // 197 * 16 = 3152 blocks
    gemm256_mfma<<<gl, dim3(512), 0, stream>>>(hb, Wlmb, outp, NROWS, VOCAB, D_MODEL);
}

// Round 11
// 2034.070 us; speedup vs baseline: 1.5634x; 1.0434x over previous
//
#include <hip/hip_runtime.h>
#include <hip/hip_bf16.h>
#include <math.h>

#define D_MODEL 768
#define N_HEAD  12
#define HEAD    64
#define SEQ     1024
#define NLAYER  6
#define BATCH   4
#define NROWS   (BATCH*SEQ)   // 4096
#define VOCAB   50257
#define VPAD    50432         // 197*256
#define DFFN    3072
#define DQKV    2304

typedef __attribute__((ext_vector_type(8))) __bf16 bf16x8;
typedef __attribute__((ext_vector_type(4))) float f32x4;
typedef __attribute__((ext_vector_type(4))) unsigned short u16x4;
typedef __attribute__((ext_vector_type(8))) unsigned short u16x8;

__device__ inline unsigned short f2bf(float x) {
    __hip_bfloat16 h = __float2bfloat16(x);
    return *reinterpret_cast<unsigned short*>(&h);
}

// ---------------- embedding ----------------
__global__ __launch_bounds__(256)
void embed_kernel(const int* __restrict__ idx, const float* __restrict__ tok,
                  const float* __restrict__ pos, float* __restrict__ x) {
    int row = blockIdx.x;
    int t = idx[row];
    int s = row & (SEQ - 1);
    const float* tp = tok + (size_t)t * D_MODEL;
    const float* pp = pos + (size_t)s * D_MODEL;
    float* xp = x + (size_t)row * D_MODEL;
    for (int i = threadIdx.x; i < D_MODEL; i += 256) xp[i] = tp[i] + pp[i];
}

// ---------------- layernorm: fp32 in, bf16 out ----------------
__global__ __launch_bounds__(256)
void ln_kernel(const float* __restrict__ in, const float* __restrict__ gw,
               const float* __restrict__ bw, unsigned short* __restrict__ out) {
    int row = blockIdx.x;
    int tid = threadIdx.x;
    const float* x = in + (size_t)row * D_MODEL;
    float v0 = x[tid], v1 = x[tid + 256], v2 = x[tid + 512];
    float s  = v0 + v1 + v2;
    float sq = v0*v0 + v1*v1 + v2*v2;
    #pragma unroll
    for (int o = 1; o < 64; o <<= 1) { s += __shfl_xor(s, o); sq += __shfl_xor(sq, o); }
    __shared__ float red[8];
    int wave = tid >> 6;
    if ((tid & 63) == 0) { red[wave] = s; red[4 + wave] = sq; }
    __syncthreads();
    s  = red[0] + red[1] + red[2] + red[3];
    sq = red[4] + red[5] + red[6] + red[7];
    float mean = s * (1.0f / D_MODEL);
    float var  = sq * (1.0f / D_MODEL) - mean * mean;
    float rstd = rsqrtf(var + 1e-5f);
    unsigned short* op = out + (size_t)row * D_MODEL;
    op[tid]       = f2bf((v0 - mean) * rstd * gw[tid]       + bw[tid]);
    op[tid + 256] = f2bf((v1 - mean) * rstd * gw[tid + 256] + bw[tid + 256]);
    op[tid + 512] = f2bf((v2 - mean) * rstd * gw[tid + 512] + bw[tid + 512]);
}

// ---------------- weight conversion (vectorized) ----------------
template<int MODE>
__global__ __launch_bounds__(256)
void conv_transpose(const float* __restrict__ in, unsigned short* __restrict__ out,
                    int K, int N, size_t inLstride, size_t outLstride) {
    __shared__ float t[64][65];
    const int tid = threadIdx.x;
    const int n0 = blockIdx.x * 64, k0 = blockIdx.y * 64;
    const float* ip = in + blockIdx.z * inLstride;
    unsigned short* op = out + blockIdx.z * outLstride;
    {
        const int kk = tid >> 4, nq = tid & 15;
        #pragma unroll
        for (int p = 0; p < 4; ++p) {
            int k = kk + p * 16;
            float4 v;
            if (MODE == 0) v = *reinterpret_cast<const float4*>(&ip[(size_t)(k0 + k) * N + n0 + nq * 4]);
            else           v = *reinterpret_cast<const float4*>(&ip[((size_t)(n0 >> 6) * K + (k0 + k)) * 64 + nq * 4]);
            t[k][nq * 4 + 0] = v.x; t[k][nq * 4 + 1] = v.y;
            t[k][nq * 4 + 2] = v.z; t[k][nq * 4 + 3] = v.w;
        }
    }
    __syncthreads();
    {
        const int n = tid >> 2, kq = tid & 3;
        unsigned short buf[16];
        #pragma unroll
        for (int j = 0; j < 16; ++j) buf[j] = f2bf(t[kq * 16 + j][n]);
        unsigned short* dst = &op[(size_t)(n0 + n) * K + k0 + kq * 16];
        *reinterpret_cast<u16x8*>(dst)     = *reinterpret_cast<u16x8*>(&buf[0]);
        *reinterpret_cast<u16x8*>(dst + 8) = *reinterpret_cast<u16x8*>(&buf[8]);
    }
}

__global__ __launch_bounds__(256)
void conv_lm(const float* __restrict__ in, unsigned short* __restrict__ out) {
    const int nchunks = VPAD * D_MODEL / 4;
    const int vchunks = VOCAB * D_MODEL / 4;
    for (int i = blockIdx.x * 256 + threadIdx.x; i < nchunks; i += gridDim.x * 256) {
        u16x4 o;
        if (i < vchunks) {
            float4 v = reinterpret_cast<const float4*>(in)[i];
            o[0] = f2bf(v.x); o[1] = f2bf(v.y); o[2] = f2bf(v.z); o[3] = f2bf(v.w);
        } else { o[0] = 0; o[1] = 0; o[2] = 0; o[3] = 0; }
        reinterpret_cast<u16x4*>(out)[i] = o;
    }
}

__global__ __launch_bounds__(256)
void conv_bias(const float* __restrict__ bq, const float* __restrict__ bk,
               const float* __restrict__ bv, float* __restrict__ out) {
    int i = blockIdx.x * 256 + threadIdx.x;
    if (i >= NLAYER * DQKV) return;
    int l = i / DQKV, n = i % DQKV;
    float v;
    if (n < 768)        v = bq[l * 768 + n];
    else if (n < 1536)  v = bk[l * 768 + n - 768];
    else                v = bv[l * 768 + n - 1536];
    out[i] = v;
}

// ---------------- 256x256 bf16 MFMA GEMM (logits), BK=64, 128 KiB ----------------
// r7-proven config: issue-early full-tile staging, one vmcnt(0)+barrier per
// K-tile, chunk^=(row&7) swizzle (conflict-free for 128B rows), setprio.
__global__ __launch_bounds__(512)
void gemm256_mfma(const unsigned short* __restrict__ A, const unsigned short* __restrict__ B,
                  float* __restrict__ C, int M, int N, int K) {
    __shared__ unsigned short smem[2 * 2 * 16384];   // 128 KiB
    const int nwg = gridDim.x;
    const int t0 = (blockIdx.x & 7) * (nwg >> 3) + (blockIdx.x >> 3);
    const int MT = M >> 8;
    const int NBX = nwg / MT;
    const int srsize = NBX * 8;
    const int sr = t0 / srsize;
    const int rem = t0 - sr * srsize;
    const int bx = rem >> 3;
    const int by = sr * 8 + (rem & 7);
    const int bm = by * 256, bn = bx * 256;
    const int tid = threadIdx.x;
    const int l = tid & 63, w = tid >> 6;
    const int wm = w >> 2, wn = w & 3;
    const int lr = l & 15, lc = l >> 4;
    f32x4 acc[8][4] = {};

    auto stage = [&](int k0, int buf) {
        #pragma unroll
        for (int p = 0; p < 4; ++p) {
            int d16 = p * 512 + tid;
            int row = d16 >> 3, cph = d16 & 7;
            int clog = cph ^ (row & 7);
            const unsigned short* ga = A + (size_t)(bm + row) * K + k0 + clog * 8;
            __builtin_amdgcn_global_load_lds(
                (const __attribute__((address_space(1))) unsigned int*)ga,
                (__attribute__((address_space(3))) unsigned int*)(&smem[buf * 32768 + d16 * 8]), 16, 0, 0);
        }
        #pragma unroll
        for (int p = 0; p < 4; ++p) {
            int d16 = p * 512 + tid;
            int row = d16 >> 3, cph = d16 & 7;
            int clog = cph ^ (row & 7);
            const unsigned short* gb = B + (size_t)(bn + row) * K + k0 + clog * 8;
            __builtin_amdgcn_global_load_lds(
                (const __attribute__((address_space(1))) unsigned int*)gb,
                (__attribute__((address_space(3))) unsigned int*)(&smem[buf * 32768 + 16384 + d16 * 8]), 16, 0, 0);
        }
    };

    auto compute = [&](int buf) {
        const unsigned short* Ab = &smem[buf * 32768];
        const unsigned short* Bb = &smem[buf * 32768 + 16384];
        #pragma unroll
        for (int qm = 0; qm < 2; ++qm) {
            bf16x8 af[2][4];
            #pragma unroll
            for (int ks = 0; ks < 2; ++ks)
                #pragma unroll
                for (int mi = 0; mi < 4; ++mi) {
                    int row = wm * 128 + qm * 64 + mi * 16 + lr;
                    af[ks][mi] = *reinterpret_cast<const bf16x8*>(
                        &Ab[row * 64 + (((ks * 4 + lc) ^ (row & 7)) * 8)]);
                }
            #pragma unroll
            for (int qn = 0; qn < 2; ++qn) {
                bf16x8 bfr[2][2];
                #pragma unroll
                for (int ks = 0; ks < 2; ++ks)
                    #pragma unroll
                    for (int ni = 0; ni < 2; ++ni) {
                        int col = wn * 64 + qn * 32 + ni * 16 + lr;
                        bfr[ks][ni] = *reinterpret_cast<const bf16x8*>(
                            &Bb[col * 64 + (((ks * 4 + lc) ^ (col & 7)) * 8)]);
                    }
                __builtin_amdgcn_s_setprio(1);
                #pragma unroll
                for (int ks = 0; ks < 2; ++ks)
                    #pragma unroll
                    for (int mi = 0; mi < 4; ++mi)
                        #pragma unroll
                        for (int ni = 0; ni < 2; ++ni)
                            acc[qm * 4 + mi][qn * 2 + ni] = __builtin_amdgcn_mfma_f32_16x16x32_bf16(
                                af[ks][mi], bfr[ks][ni], acc[qm * 4 + mi][qn * 2 + ni], 0, 0, 0);
                __builtin_amdgcn_s_setprio(0);
            }
        }
    };

    const int NT = K >> 6;
    stage(0, 0);
    asm volatile("s_waitcnt vmcnt(0)" ::: "memory");
    __builtin_amdgcn_s_barrier();
    for (int t = 0; t < NT; ++t) {
        const int cur = t & 1;
        if (t + 1 < NT) stage((t + 1) << 6, cur ^ 1);
        compute(cur);
        if (t + 1 < NT) {
            asm volatile("s_waitcnt vmcnt(0)" ::: "memory");
            __builtin_amdgcn_s_barrier();
        }
    }

    #pragma unroll
    for (int i = 0; i < 8; ++i) {
        #pragma unroll
        for (int r = 0; r < 4; ++r) {
            const int row = bm + wm * 128 + i * 16 + lc * 4 + r;
            #pragma unroll
            for (int j = 0; j < 4; ++j) {
                const int col = bn + wn * 64 + j * 16 + lr;
                if (col < N) C[(size_t)row * N + col] = acc[i][j][r];
            }
        }
    }
}

// ---------------- BMx128 bf16 MFMA GEMM (layer GEMMs) ----------------
// Swapped-operand MFMA: lane holds 4 CONSECUTIVE COLS -> float4/u16x4 epilogue.
template<int BM, int OUTF /*0=f32,1=bf16*/, bool GELU, bool RES>
__global__ __launch_bounds__(256)
void gemm_sched(const unsigned short* __restrict__ A, const unsigned short* __restrict__ B,
                const float* __restrict__ bias, const float* __restrict__ res,
                void* __restrict__ Cout, int M, int N, int K) {
    constexpr int ABUF = BM * 64;
    constexpr int TBUF = (BM + 128) * 64;
    __shared__ unsigned short smem[2 * TBUF];
    const int nwg = gridDim.x;
    const int t0 = (blockIdx.x & 7) * (nwg >> 3) + (blockIdx.x >> 3);
    const int MT = M / BM;
    const int NBX = nwg / MT;
    const int srsize = NBX * 8;
    const int sr = t0 / srsize;
    const int rem = t0 - sr * srsize;
    const int bx = rem >> 3;
    const int by = sr * 8 + (rem & 7);
    const int bm = by * BM, bn = bx * 128;
    const int tid = threadIdx.x;
    const int l = tid & 63, w = tid >> 6;
    constexpr int MI = (BM == 128) ? 4 : 2;
    const int wr = (BM == 128) ? (w >> 1) * 64 : (w & 1) * 32;
    const int wc = (BM == 128) ? (w & 1) * 64 : (w >> 1) * 64;
    const int lr = l & 15, lc = l >> 4;
    f32x4 acc[MI][4] = {};

    auto stage = [&](int k0, int buf) {
        #pragma unroll
        for (int p = 0; p < BM * 8 / 256; ++p) {
            int d16 = p * 256 + tid;
            int row = d16 >> 3, cph = d16 & 7;
            int clog = cph ^ (row & 7);
            const unsigned short* ga = A + (size_t)(bm + row) * K + k0 + clog * 8;
            __builtin_amdgcn_global_load_lds(
                (const __attribute__((address_space(1))) unsigned int*)ga,
                (__attribute__((address_space(3))) unsigned int*)(&smem[buf * TBUF + d16 * 8]), 16, 0, 0);
        }
        #pragma unroll
        for (int p = 0; p < 4; ++p) {
            int d16 = p * 256 + tid;
            int row = d16 >> 3, cph = d16 & 7;
            int clog = cph ^ (row & 7);
            const unsigned short* gb = B + (size_t)(bn + row) * K + k0 + clog * 8;
            __builtin_amdgcn_global_load_lds(
                (const __attribute__((address_space(1))) unsigned int*)gb,
                (__attribute__((address_space(3))) unsigned int*)(&smem[buf * TBUF + ABUF + d16 * 8]), 16, 0, 0);
        }
    };

    auto compute = [&](int buf) {
        const unsigned short* Ab = &smem[buf * TBUF];
        const unsigned short* Bb = &smem[buf * TBUF + ABUF];
        #pragma unroll
        for (int ks = 0; ks < 2; ++ks) {
            bf16x8 af[MI], bfr[4];
            #pragma unroll
            for (int mi = 0; mi < MI; ++mi) {
                int row = wr + mi * 16 + lr;
                af[mi] = *reinterpret_cast<const bf16x8*>(
                    &Ab[row * 64 + (((ks * 4 + lc) ^ (row & 7)) * 8)]);
            }
            #pragma unroll
            for (int ni = 0; ni < 4; ++ni) {
                int col = wc + ni * 16 + lr;
                bfr[ni] = *reinterpret_cast<const bf16x8*>(
                    &Bb[col * 64 + (((ks * 4 + lc) ^ (col & 7)) * 8)]);
            }
            __builtin_amdgcn_s_setprio(1);
            #pragma unroll
            for (int mi = 0; mi < MI; ++mi)
                #pragma unroll
                for (int ni = 0; ni < 4; ++ni)
                    acc[mi][ni] = __builtin_amdgcn_mfma_f32_16x16x32_bf16(
                        bfr[ni], af[mi], acc[mi][ni], 0, 0, 0);   // SWAPPED
            __builtin_amdgcn_s_setprio(0);
        }
    };

    const int NT = K >> 6;
    stage(0, 0);
    asm volatile("s_waitcnt vmcnt(0)" ::: "memory");
    __builtin_amdgcn_s_barrier();
    for (int t = 0; t < NT; ++t) {
        const int cur = t & 1;
        if (t + 1 < NT) stage((t + 1) << 6, cur ^ 1);
        compute(cur);
        if (t + 1 < NT) {
            asm volatile("s_waitcnt vmcnt(0)" ::: "memory");
            __builtin_amdgcn_s_barrier();
        }
    }

    #pragma unroll
    for (int mi = 0; mi < MI; ++mi) {
        const int row = bm + wr + mi * 16 + lr;
        #pragma unroll
        for (int ni = 0; ni < 4; ++ni) {
            const int colb = bn + wc + ni * 16 + lc * 4;
            f32x4 v = acc[mi][ni];
            if (bias) v += *reinterpret_cast<const f32x4*>(&bias[colb]);
            if (GELU) {
                #pragma unroll
                for (int r = 0; r < 4; ++r)
                    v[r] = 0.5f * v[r] * (1.0f + erff(v[r] * 0.70710678118654752f));
            }
            if (RES) v += *reinterpret_cast<const f32x4*>(&res[(size_t)row * N + colb]);
            if (OUTF == 0) {
                *reinterpret_cast<f32x4*>(&((float*)Cout)[(size_t)row * N + colb]) = v;
            } else {
                u16x4 o;
                o[0] = f2bf(v[0]); o[1] = f2bf(v[1]); o[2] = f2bf(v[2]); o[3] = f2bf(v[3]);
                *reinterpret_cast<u16x4*>(&((unsigned short*)Cout)[(size_t)row * N + colb]) = o;
            }
        }
    }
}

// ---------------- bf16 MFMA causal flash attention ----------------
// 128 q-rows/block, 8 waves. Double-buffered K/V LDS, issue-early reg staging,
// ONE barrier per KV tile (writes to buf^1 never collide with reads of buf).
__global__ __launch_bounds__(512)
void attn_mfma(const unsigned short* __restrict__ qkv, unsigned short* __restrict__ ao) {
    const int qt = gridDim.x - 1 - blockIdx.x;   // heavy blocks first
    const int h = blockIdx.y, b = blockIdx.z;
    const int tid = threadIdx.x;
    const int w = tid >> 6, l = tid & 63;
    const int c = l & 15, g = l >> 4;

    __shared__ unsigned short Ks[2][32 * 64];
    __shared__ unsigned short Vt[2][64 * 40];
    __shared__ unsigned int   Ps[8][16 * 20];

    const unsigned short* base = qkv + (size_t)(b * SEQ) * DQKV + h * HEAD;
    const int q0 = qt * 128 + w * 16;

    bf16x8 qf[2];
    {
        const unsigned short* qp = base + (size_t)(q0 + c) * DQKV + g * 8;
        qf[0] = *reinterpret_cast<const bf16x8*>(qp);
        qf[1] = *reinterpret_cast<const bf16x8*>(qp + 32);
    }

    f32x4 o_acc[4] = {};
    float m_run[4]  = {-INFINITY, -INFINITY, -INFINITY, -INFINITY};
    float l_run[4]  = {0.f, 0.f, 0.f, 0.f};

    const int srow = tid >> 4, sch8 = tid & 15;
    const int scj = sch8 >> 1, sh = sch8 & 1;
    const int vd = tid & 63, vw = tid >> 6;

    u16x4 kreg;
    unsigned short vreg[4];
    auto loadKV = [&](int kt) {
        kreg = *reinterpret_cast<const u16x4*>(
            base + (size_t)(kt * 32 + srow) * DQKV + 768 + sch8 * 4);
        #pragma unroll
        for (int j = 0; j < 4; ++j)
            vreg[j] = base[(size_t)(kt * 32 + vw * 4 + j) * DQKV + 1536 + vd];
    };

    const int nkt = 4 * qt + 4;
    loadKV(0);
    for (int kt = 0; kt < nkt; ++kt) {
        const int bf = kt & 1;
        // write staged regs to this tile's buffer
        *reinterpret_cast<u16x4*>(&Ks[bf][srow * 64 + ((scj ^ (srow & 7)) * 8) + sh * 4]) = kreg;
        {
            uint2 pk;
            pk.x = vreg[0] | ((unsigned)vreg[1] << 16);
            pk.y = vreg[2] | ((unsigned)vreg[3] << 16);
            *reinterpret_cast<uint2*>(&Vt[bf][vd * 40 + vw * 4]) = pk;
        }
        __syncthreads();
        if (kt + 1 < nkt) loadKV(kt + 1);    // in flight under compute

        f32x4 s_acc[2] = {};
        #pragma unroll
        for (int t = 0; t < 2; ++t) {
            const int kr = t * 16 + c;
            #pragma unroll
            for (int ks = 0; ks < 2; ++ks) {
                bf16x8 kf = *reinterpret_cast<const bf16x8*>(
                    &Ks[bf][kr * 64 + (((ks * 4 + g) ^ (kr & 7)) * 8)]);
                s_acc[t] = __builtin_amdgcn_mfma_f32_16x16x32_bf16(qf[ks], kf, s_acc[t], 0, 0, 0);
            }
        }
        float sc[2][4];
        #pragma unroll
        for (int t = 0; t < 2; ++t) {
            const int kglob = kt * 32 + t * 16 + c;
            #pragma unroll
            for (int r = 0; r < 4; ++r) {
                float v = s_acc[t][r] * 0.125f;
                sc[t][r] = (kglob > q0 + g * 4 + r) ? -1e30f : v;
            }
        }
        float pout[2][4];
        #pragma unroll
        for (int r = 0; r < 4; ++r) {
            float tmax = fmaxf(sc[0][r], sc[1][r]);
            #pragma unroll
            for (int ms = 1; ms < 16; ms <<= 1) tmax = fmaxf(tmax, __shfl_xor(tmax, ms));
            float mnew = fmaxf(m_run[r], tmax);
            float alpha = __expf(m_run[r] - mnew);
            float p0 = __expf(sc[0][r] - mnew);
            float p1 = __expf(sc[1][r] - mnew);
            float psum = p0 + p1;
            #pragma unroll
            for (int ms = 1; ms < 16; ms <<= 1) psum += __shfl_xor(psum, ms);
            l_run[r] = l_run[r] * alpha + psum;
            m_run[r] = mnew;
            #pragma unroll
            for (int dt = 0; dt < 4; ++dt) o_acc[dt][r] *= alpha;
            pout[0][r] = p0; pout[1][r] = p1;
        }
        #pragma unroll
        for (int t = 0; t < 2; ++t) {
            #pragma unroll
            for (int r = 0; r < 4; ++r) {
                int my = f2bf(pout[t][r]);
                int part = __shfl_xor(my, 1);
                unsigned int word = (c & 1) ? ((unsigned)(part & 0xffff) | ((unsigned)my << 16))
                                            : ((unsigned)(my & 0xffff) | ((unsigned)part << 16));
                Ps[w][(g * 4 + r) * 20 + t * 8 + (c >> 1)] = word;
            }
        }
        uint4 praw = *reinterpret_cast<const uint4*>(&Ps[w][c * 20 + g * 4]);
        bf16x8 pf = *reinterpret_cast<const bf16x8*>(&praw);
        #pragma unroll
        for (int dt = 0; dt < 4; ++dt) {
            bf16x8 vf = *reinterpret_cast<const bf16x8*>(&Vt[bf][(dt * 16 + c) * 40 + g * 8]);
            o_acc[dt] = __builtin_amdgcn_mfma_f32_16x16x32_bf16(pf, vf, o_acc[dt], 0, 0, 0);
        }
        // no trailing barrier: next iteration writes buf^1 only
    }

    float inv[4];
    #pragma unroll
    for (int r = 0; r < 4; ++r) inv[r] = 1.0f / l_run[r];
    #pragma unroll
    for (int r = 0; r < 4; ++r) {
        unsigned short* op = ao + (size_t)(b * SEQ + q0 + g * 4 + r) * D_MODEL + h * HEAD + c;
        #pragma unroll
        for (int dt = 0; dt < 4; ++dt)
            op[dt * 16] = f2bf(o_acc[dt][r] * inv[r]);
    }
}

extern "C" void kernel_launch(void* const* d_in, const int* in_sizes, int n_in,
                              void* d_out, int out_size, void* d_ws, size_t ws_size,
                              hipStream_t stream) {
    const int*   idx     = (const int*)  d_in[0];
    const float* tok_emb = (const float*)d_in[1];
    const float* pos_emb = (const float*)d_in[2];
    const float* Wq      = (const float*)d_in[3];
    const float* bq      = (const float*)d_in[4];
    const float* Wk      = (const float*)d_in[5];
    const float* bk      = (const float*)d_in[6];
    const float* Wv      = (const float*)d_in[7];
    const float* bv      = (const float*)d_in[8];
    const float* Wproj   = (const float*)d_in[9];
    const float* bproj   = (const float*)d_in[10];
    const float* ln1g    = (const float*)d_in[11];
    const float* ln1b    = (const float*)d_in[12];
    const float* ln2g    = (const float*)d_in[13];
    const float* ln2b    = (const float*)d_in[14];
    const float* Wf1     = (const float*)d_in[15];
    const float* bf1     = (const float*)d_in[16];
    const float* Wf2     = (const float*)d_in[17];
    const float* bf2     = (const float*)d_in[18];
    const float* lnfg    = (const float*)d_in[19];
    const float* lnfb    = (const float*)d_in[20];
    const float* Wlm     = (const float*)d_in[21];
    float* outp = (float*)d_out;

    char* basep = (char*)d_ws;
    size_t off = 0;
    auto alloc = [&](size_t bytes) -> void* {
        void* p = basep + off;
        off = (off + bytes + 255) & ~(size_t)255;
        return p;
    };
    float*          x      = (float*)         alloc((size_t)NROWS * D_MODEL * 4);
    unsigned short* qkv    = (unsigned short*)alloc((size_t)NROWS * DQKV * 2);
    unsigned short* hb     = (unsigned short*)alloc((size_t)NROWS * D_MODEL * 2);
    unsigned short* ao     = (unsigned short*)alloc((size_t)NROWS * D_MODEL * 2);
    unsigned short* mid    = (unsigned short*)alloc((size_t)NROWS * DFFN * 2);
    unsigned short* Wqkvb  = (unsigned short*)alloc((size_t)NLAYER * DQKV * D_MODEL * 2);
    unsigned short* Wprojb = (unsigned short*)alloc((size_t)NLAYER * D_MODEL * D_MODEL * 2);
    unsigned short* Wf1b   = (unsigned short*)alloc((size_t)NLAYER * DFFN * D_MODEL * 2);
    unsigned short* Wf2b   = (unsigned short*)alloc((size_t)NLAYER * D_MODEL * DFFN * 2);
    unsigned short* Wlmb   = (unsigned short*)alloc((size_t)VPAD * D_MODEL * 2);
    float*          bqkv   = (float*)         alloc((size_t)NLAYER * DQKV * 4);

    dim3 blk(256);

    conv_lm<<<2048, blk, 0, stream>>>(Wlm, Wlmb);
    conv_transpose<1><<<dim3(12, 12, 6), blk, 0, stream>>>(Wq, Wqkvb,             768, 768,  (size_t)768*768,  (size_t)DQKV*768);
    conv_transpose<1><<<dim3(12, 12, 6), blk, 0, stream>>>(Wk, Wqkvb + 768*768,   768, 768,  (size_t)768*768,  (size_t)DQKV*768);
    conv_transpose<1><<<dim3(12, 12, 6), blk, 0, stream>>>(Wv, Wqkvb + 2*768*768, 768, 768,  (size_t)768*768,  (size_t)DQKV*768);
    conv_transpose<0><<<dim3(12, 12, 6), blk, 0, stream>>>(Wproj, Wprojb,         768, 768,  (size_t)768*768,  (size_t)768*768);
    conv_transpose<0><<<dim3(48, 12, 6), blk, 0, stream>>>(Wf1, Wf1b,             768, 3072, (size_t)768*3072, (size_t)3072*768);
    conv_transpose<0><<<dim3(12, 48, 6), blk, 0, stream>>>(Wf2, Wf2b,             3072, 768, (size_t)3072*768, (size_t)768*3072);
    conv_bias<<<(NLAYER * DQKV + 255) / 256, blk, 0, stream>>>(bq, bk, bv, bqkv);

    embed_kernel<<<NROWS, blk, 0, stream>>>(idx, tok_emb, pos_emb, x);

    dim3 gqkv(32 * 18);                  // BM=128, 576 blocks
    dim3 g768s(64 * 6);                  // BM=64,  384 blocks (proj, FFN2)
    dim3 g3072(32 * 24);                 // BM=128, 768 blocks (FFN1)
    dim3 ga(SEQ / 128, N_HEAD, BATCH);   // (8, 12, 4)

    for (int li = 0; li < NLAYER; ++li) {
        ln_kernel<<<NROWS, blk, 0, stream>>>(x, ln1g + li * D_MODEL, ln1b + li * D_MODEL, hb);

        gemm_sched<128, 1, false, false><<<gqkv, blk, 0, stream>>>(
            hb, Wqkvb + (size_t)li * DQKV * D_MODEL, bqkv + li * DQKV, nullptr,
            qkv, NROWS, DQKV, D_MODEL);

        attn_mfma<<<ga, dim3(512), 0, stream>>>(qkv, ao);

        gemm_sched<64, 0, false, true><<<g768s, blk, 0, stream>>>(
            ao, Wprojb + (size_t)li * D_MODEL * D_MODEL, bproj + li * D_MODEL, x,
            x, NROWS, D_MODEL, D_MODEL);

        ln_kernel<<<NROWS, blk, 0, stream>>>(x, ln2g + li * D_MODEL, ln2b + li * D_MODEL, hb);

        gemm_sched<128, 1, true, false><<<g3072, blk, 0, stream>>>(
            hb, Wf1b + (size_t)li * DFFN * D_MODEL, bf1 + li * DFFN, nullptr,
            mid, NROWS, DFFN, D_MODEL);

        gemm_sched<64, 0, false, true><<<g768s, blk, 0, stream>>>(
            mid, Wf2b + (size_t)li * D_MODEL * DFFN, bf2 + li * D_MODEL, x,
            x, NROWS, D_MODEL, DFFN);
    }

    ln_kernel<<<NROWS, blk, 0, stream>>>(x, lnfg, lnfb, hb);

    dim3 gl((VPAD / 256) * (NROWS / 256));   // 197 * 16 = 3152 blocks
    gemm256_mfma<<<gl, dim3(512), 0, stream>>>(hb, Wlmb, outp, NROWS, VOCAB, D_MODEL);
}